// Round 9
// baseline (378.784 us; speedup 1.0000x reference)
//
#include <hip/hip_runtime.h>
#include <math.h>

typedef __attribute__((ext_vector_type(8))) __bf16 bf16x8;
typedef __attribute__((ext_vector_type(4))) float f32x4;

__device__ __forceinline__ float elu_f(float v) {
    return v > 0.f ? v : (expf(v) - 1.f);
}

// ---------------------------------------------------------------------------
// Conv weight reorder: w[co][ci][K] fp32 -> wT[k][co][ci] bf16 (all 4 convs).
// ---------------------------------------------------------------------------
__global__ __launch_bounds__(256) void prep_weights(
    const float* __restrict__ w1, const float* __restrict__ w2,
    const float* __restrict__ w3, const float* __restrict__ w4,
    __bf16* __restrict__ t1, __bf16* __restrict__ t2,
    __bf16* __restrict__ t3, __bf16* __restrict__ t4)
{
    int idx = blockIdx.x * 256 + threadIdx.x;
    if (idx < 81920) {
        int k = idx / 4096, r = idx - k * 4096, co = r >> 6, ci = r & 63;
        t1[idx] = (__bf16)w1[(co * 64 + ci) * 20 + k];
    } else if (idx < 163840) {
        int j = idx - 81920;
        int k = j / 4096, r = j - k * 4096, co = r >> 6, ci = r & 63;
        t2[j] = (__bf16)w2[(co * 64 + ci) * 20 + k];
    } else if (idx < 188416) {
        int j = idx - 163840;
        int k = j / 4096, r = j - k * 4096, co = r >> 6, ci = r & 63;
        t3[j] = (__bf16)w3[(co * 64 + ci) * 6 + k];
    } else if (idx < 212992) {
        int j = idx - 188416;
        int k = j / 4096, r = j - k * 4096, co = r >> 6, ci = r & 63;
        t4[j] = (__bf16)w4[(co * 64 + ci) * 6 + k];
    }
}

// ---------------------------------------------------------------------------
// Tiled transpose+convert with hi/lo split for GIN weights. 57 blocks.
// ---------------------------------------------------------------------------
__global__ __launch_bounds__(256) void prep_tr(
    const float* __restrict__ g0w1, const float* __restrict__ g0w2,
    const float* __restrict__ g1w1, const float* __restrict__ g1w2,
    const float* __restrict__ g2w1, const float* __restrict__ g2w2,
    __bf16* __restrict__ d0, __bf16* __restrict__ d1, __bf16* __restrict__ d2,
    __bf16* __restrict__ d3, __bf16* __restrict__ d4, __bf16* __restrict__ d5)
{
    int bid = blockIdx.x;
    const float* src; __bf16* dst; int K, O, Kpad, Opad, tile;
    if (bid < 4)       { src = g0w1; dst = d0; K = 35;   O = 256; Kpad = 64;   Opad = 256; tile = bid; }
    else if (bid < 20) { src = g0w2; dst = d1; K = 256;  O = 256; Kpad = 256;  Opad = 256; tile = bid - 4; }
    else if (bid < 36) { src = g1w1; dst = d2; K = 256;  O = 256; Kpad = 256;  Opad = 256; tile = bid - 20; }
    else if (bid < 52) { src = g1w2; dst = d3; K = 256;  O = 256; Kpad = 256;  Opad = 256; tile = bid - 36; }
    else if (bid < 56) { src = g2w1; dst = d4; K = 256;  O = 35;  Kpad = 256;  Opad = 64;  tile = bid - 52; }
    else               { src = g2w2; dst = d5; K = 35;   O = 35;  Kpad = 64;   Opad = 64;  tile = 0; }
    int ktiles = Kpad >> 6;
    int ot = tile / ktiles, kt = tile - ot * ktiles;
    int k0 = kt * 64, o0 = ot * 64;
    size_t LOFF = (size_t)Opad * Kpad;
    __shared__ float tl[64][68];
    int c = threadIdx.x & 63, rr = threadIdx.x >> 6;
    #pragma unroll
    for (int it = 0; it < 16; ++it) {
        int r = rr + it * 4;
        int kk = k0 + r, oo = o0 + c;
        tl[r][c] = (kk < K && oo < O) ? src[(size_t)kk * O + oo] : 0.f;
    }
    __syncthreads();
    #pragma unroll
    for (int it = 0; it < 16; ++it) {
        int r = rr + it * 4;
        float v = tl[c][r];
        __bf16 hi = (__bf16)v;
        float lo = v - (float)hi;
        size_t pos = (size_t)(o0 + r) * Kpad + k0 + c;
        dst[pos] = hi;
        dst[LOFF + pos] = (__bf16)lo;
    }
}

// ---------------------------------------------------------------------------
// MFMA conv1d, Cin=Cout=64. Output [n][t][64co] bf16. Pure-LDS K-loop.
// IMODE 0 staging is ci-inner: 64 consecutive lanes write 64 consecutive ci
// of the same position row -> LDS write banks = ci/2 (2-way, free). The old
// t-inner map was a 32-way write conflict (the 5M SQ_LDS_BANK_CONFLICT).
// ---------------------------------------------------------------------------
template<int K, int STRIDE, int PAD, bool DO_BN, int IMODE,
         int NPB, int TPN, int LIN, int LOUT, int KCHUNK>
__global__ __launch_bounds__(NPB * TPN * 64, 2) void conv_mfma(
    const void* __restrict__ xin, const __bf16* __restrict__ wT,
    const float* __restrict__ bias,
    const float* __restrict__ bn_g, const float* __restrict__ bn_b,
    const float* __restrict__ bn_m, const float* __restrict__ bn_v,
    __bf16* __restrict__ y)
{
    constexpr int THREADS = NPB * TPN * 64;
    constexpr int TBLK  = TPN * 48;
    constexpr int VSPAN = STRIDE * (TBLK - 1) + K;
    constexpr int NBUF  = (STRIDE == 2) ? 2 : 1;
    constexpr int ROWS  = (VSPAN + NBUF - 1) / NBUF;
    __shared__ __align__(16) __bf16 sx[NPB * NBUF * ROWS * 72];
    __shared__ __align__(16) __bf16 sw[KCHUNK * 64 * 72];

    const int tid = threadIdx.x;
    const int nb  = blockIdx.x * NPB;

    if constexpr (IMODE == 0) {
        const float* xg = (const float*)xin + (size_t)nb * 64 * LIN;
        constexpr int NZROWS = PAD + (VSPAN - LIN - PAD);
        if (tid < NZROWS * 64) {
            int zr = tid >> 6;
            int v = (zr < PAD) ? zr : (LIN + PAD + zr - PAD);
            sx[((v & (NBUF - 1)) * ROWS + (v >> (NBUF - 1))) * 72 + (tid & 63)] = (__bf16)0.f;
        }
        constexpr int J4 = LIN / 4;          // 100 position groups
        constexpr int NCH = J4 * 64;
        constexpr int ITER = NCH / THREADS;  // 25
        #pragma unroll
        for (int it = 0; it < ITER; ++it) {
            int idx = it * THREADS + tid;
            int v4 = idx >> 6, ci = idx & 63;    // ci-inner: conflict-free writes
            float4 f = *(const float4*)(xg + (size_t)ci * LIN + 4 * v4);
            #pragma unroll
            for (int e = 0; e < 4; ++e) {
                int v = 4 * v4 + e + PAD;
                sx[((v & (NBUF - 1)) * ROWS + (v >> (NBUF - 1))) * 72 + ci] =
                    (__bf16)((e == 0) ? f.x : (e == 1) ? f.y : (e == 2) ? f.z : f.w);
            }
        }
    } else {
        const __bf16* xg = (const __bf16*)xin;
        constexpr int NSTG = NPB * VSPAN * 8;
        constexpr int ITER = (NSTG + THREADS - 1) / THREADS;
        #pragma unroll
        for (int it = 0; it < ITER; ++it) {
            int idx = it * THREADS + tid;
            if (idx < NSTG) {
                int n_l = idx / (VSPAN * 8);
                int r   = idx - n_l * (VSPAN * 8);
                int v = r >> 3, c8 = (r & 7) * 8;
                int buf = (STRIDE == 2) ? (v & 1) : 0;
                int row = (STRIDE == 2) ? (v >> 1) : v;
                __bf16* dst = sx + ((size_t)(n_l * NBUF + buf) * ROWS + row) * 72 + c8;
                if constexpr (IMODE == 1) {
                    if (v < LIN) {
                        const __bf16* src = xg + (((size_t)(nb + n_l) * LIN + v) * 64 + c8);
                        *(uint4*)dst = *(const uint4*)src;
                    } else {
                        #pragma unroll
                        for (int e = 0; e < 8; ++e) dst[e] = (__bf16)0.f;
                    }
                } else {
                    if (v < LIN) {
                        const __bf16* s0 = xg + (((size_t)(nb + n_l) * 82 + 2 * v) * 64 + c8);
                        #pragma unroll
                        for (int e = 0; e < 8; ++e)
                            dst[e] = (__bf16)(((float)s0[e] + (float)s0[64 + e] +
                                               (float)s0[128 + e]) * (1.f / 3.f));
                    } else {
                        #pragma unroll
                        for (int e = 0; e < 8; ++e) dst[e] = (__bf16)0.f;
                    }
                }
            }
        }
    }

    const int wave = tid >> 6, lane = tid & 63;
    const int n_l  = wave / TPN, tile = wave - n_l * TPN;
    const int m    = lane & 15, quad = lane >> 4;
    const __bf16* sxn = sx + (size_t)n_l * NBUF * ROWS * 72;

    f32x4 acc[3][4];
    #pragma unroll
    for (int mi = 0; mi < 3; ++mi)
        #pragma unroll
        for (int nj = 0; nj < 4; ++nj)
            acc[mi][nj] = (f32x4){0.f, 0.f, 0.f, 0.f};

    for (int kb = 0; kb < K; kb += KCHUNK) {
        if (kb) __syncthreads();
        constexpr int WITER = KCHUNK * 64 * 8 / THREADS;
        #pragma unroll
        for (int it = 0; it < WITER; ++it) {
            int idx = it * THREADS + tid;
            int r = idx >> 3, p = idx & 7;
            *(uint4*)(sw + (size_t)r * 72 + p * 8) =
                *(const uint4*)(wT + (size_t)(kb + (r >> 6)) * 4096 + (r & 63) * 64 + p * 8);
        }
        __syncthreads();

        #pragma unroll
        for (int kp2 = 0; kp2 < KCHUNK; ++kp2) {
            const int kp = kb + kp2;
            const int buf    = (STRIDE == 2) ? (kp & 1) : 0;
            const int rowoff = (STRIDE == 2) ? (kp >> 1) : kp;
            const __bf16* abase = sxn + ((size_t)buf * ROWS + tile * 48 + m + rowoff) * 72;
            const __bf16* bbase = sw + (size_t)(kp2 * 64 + m) * 72;
            #pragma unroll
            for (int s = 0; s < 2; ++s) {
                bf16x8 af[3], bfr[4];
                #pragma unroll
                for (int mi = 0; mi < 3; ++mi)
                    af[mi] = *(const bf16x8*)(abase + mi * (16 * 72) + s * 32 + quad * 8);
                #pragma unroll
                for (int nj = 0; nj < 4; ++nj)
                    bfr[nj] = *(const bf16x8*)(bbase + nj * (16 * 72) + s * 32 + quad * 8);
                #pragma unroll
                for (int mi = 0; mi < 3; ++mi)
                    #pragma unroll
                    for (int nj = 0; nj < 4; ++nj)
                        acc[mi][nj] = __builtin_amdgcn_mfma_f32_16x16x32_bf16(
                            af[mi], bfr[nj], acc[mi][nj], 0, 0, 0);
            }
        }
    }

    #pragma unroll
    for (int nj = 0; nj < 4; ++nj) {
        const int co = nj * 16 + m;
        const float bi = bias[co];
        float scale = 1.f, shift = 0.f;
        if constexpr (DO_BN) {
            float inv = bn_g[co] / sqrtf(bn_v[co] + 1e-5f);
            scale = inv; shift = bn_b[co] - bn_m[co] * inv;
        }
        #pragma unroll
        for (int mi = 0; mi < 3; ++mi) {
            #pragma unroll
            for (int r = 0; r < 4; ++r) {
                int t = tile * 48 + mi * 16 + quad * 4 + r;
                if (t < LOUT) {
                    float v = acc[mi][nj][r] + bi;
                    v = elu_f(v);
                    if constexpr (DO_BN) v = v * scale + shift;
                    y[((size_t)(nb + n_l) * LOUT + t) * 64 + co] = (__bf16)v;
                }
            }
        }
    }
}

// ---------------------------------------------------------------------------
// Attention pooling over crop dim. One block per (b,c). h: [512][35][64] bf16.
// ---------------------------------------------------------------------------
__global__ __launch_bounds__(256) void attn_pool_k(
    const __bf16* __restrict__ h, const float* __restrict__ W,
    const float* __restrict__ ab, const float* __restrict__ u,
    float* __restrict__ out)
{
    const int b = blockIdx.x >> 6;
    const int c = blockIdx.x & 63;
    __shared__ float sh[16 * 35];
    __shared__ float slog[16];
    __shared__ float sred[4];
    __shared__ float salpha[16];
    const int tid = threadIdx.x;
    for (int idx = tid; idx < 16 * 35; idx += 256) {
        int s = idx / 35, hh = idx - s * 35;
        sh[idx] = (float)h[((size_t)(b * 16 + s) * 35 + hh) * 64 + c];
    }
    __syncthreads();
    float Wc[35];
    #pragma unroll
    for (int k = 0; k < 35; ++k) Wc[k] = W[k * 256 + tid];
    const float myb = ab[tid], myu = u[tid];
    for (int s = 0; s < 16; ++s) {
        float dot = myb;
        #pragma unroll
        for (int k = 0; k < 35; ++k) dot = fmaf(sh[s * 35 + k], Wc[k], dot);
        float val = tanhf(dot) * myu;
        #pragma unroll
        for (int off = 32; off > 0; off >>= 1) val += __shfl_down(val, off, 64);
        if ((tid & 63) == 0) sred[tid >> 6] = val;
        __syncthreads();
        if (tid == 0) slog[s] = sred[0] + sred[1] + sred[2] + sred[3];
        __syncthreads();
    }
    if (tid == 0) {
        float mx = slog[0];
        for (int s = 1; s < 16; ++s) mx = fmaxf(mx, slog[s]);
        float sum = 0.f, e[16];
        for (int s = 0; s < 16; ++s) { e[s] = expf(slog[s] - mx); sum += e[s]; }
        float inv = 1.f / sum;
        for (int s = 0; s < 16; ++s) salpha[s] = e[s] * inv;
    }
    __syncthreads();
    if (tid < 35) {
        float acc = 0.f;
        for (int s = 0; s < 16; ++s) acc = fmaf(sh[s * 35 + tid], salpha[s], acc);
        out[((size_t)(b * 64 + c)) * 35 + tid] = elu_f(acc);
    }
}

// ---------------------------------------------------------------------------
// Fused GIN stack, split-bf16 (hi/lo), 1024 threads = 16 waves per block.
// Each wave owns a 16-wide output strip (4x1 fragments) -> 4x the latency
// hiding of the old 4-wave version. Same op order per accumulator.
// ---------------------------------------------------------------------------
#define APLANE (64 * 264)

__device__ __forceinline__ void gin_gemm_dev(
    const __bf16* As,                 // hi plane; lo at As+APLANE
    const __bf16* __restrict__ Wg, int Kpad, int wlo, int Kout,
    const float* __restrict__ bias,
    int mode,                 // 0: relu->A   1: relu, +colsum ->A   2: raw->global
    __bf16* Ad, float* __restrict__ outg)
{
    const int lane = threadIdx.x & 63;
    const int wave = threadIdx.x >> 6;      // 0..15
    const int o0 = wave * 16;
    if (o0 >= ((Kout + 63) & ~63)) return;
    const int m = lane & 15, quad = lane >> 4;

    f32x4 acc[4];
    #pragma unroll
    for (int mi = 0; mi < 4; ++mi)
        acc[mi] = (f32x4){0.f, 0.f, 0.f, 0.f};

    for (int k0 = 0; k0 < Kpad; k0 += 32) {
        bf16x8 ah[4], al[4];
        #pragma unroll
        for (int mi = 0; mi < 4; ++mi) {
            const __bf16* ap = As + (size_t)(mi * 16 + m) * 264 + k0 + quad * 8;
            ah[mi] = *(const bf16x8*)ap;
            al[mi] = *(const bf16x8*)(ap + APLANE);
        }
        const __bf16* wp = Wg + (size_t)(o0 + m) * Kpad + k0 + quad * 8;
        bf16x8 bh = *(const bf16x8*)wp;
        bf16x8 bl = *(const bf16x8*)(wp + wlo);
        #pragma unroll
        for (int mi = 0; mi < 4; ++mi) {
            acc[mi] = __builtin_amdgcn_mfma_f32_16x16x32_bf16(al[mi], bh, acc[mi], 0, 0, 0);
            acc[mi] = __builtin_amdgcn_mfma_f32_16x16x32_bf16(ah[mi], bl, acc[mi], 0, 0, 0);
            acc[mi] = __builtin_amdgcn_mfma_f32_16x16x32_bf16(ah[mi], bh, acc[mi], 0, 0, 0);
        }
    }

    const int o = o0 + m;
    const bool ovalid = (o < Kout);
    const float bi = ovalid ? bias[o] : 0.f;
    float v[4][4];
    #pragma unroll
    for (int mi = 0; mi < 4; ++mi)
        #pragma unroll
        for (int r = 0; r < 4; ++r)
            v[mi][r] = acc[mi][r] + bi;
    if (mode == 2) {
        if (ovalid) {
            #pragma unroll
            for (int mi = 0; mi < 4; ++mi)
                #pragma unroll
                for (int r = 0; r < 4; ++r)
                    outg[(size_t)(mi * 16 + quad * 4 + r) * Kout + o] = v[mi][r];
        }
    } else {
        float s = 0.f;
        #pragma unroll
        for (int mi = 0; mi < 4; ++mi)
            #pragma unroll
            for (int r = 0; r < 4; ++r) {
                float rv = ovalid ? fmaxf(v[mi][r], 0.f) : 0.f;
                v[mi][r] = rv;
                s += rv;
            }
        if (mode == 1) {
            s += __shfl_xor(s, 16, 64);
            s += __shfl_xor(s, 32, 64);
        } else {
            s = 0.f;
        }
        #pragma unroll
        for (int mi = 0; mi < 4; ++mi)
            #pragma unroll
            for (int r = 0; r < 4; ++r) {
                float a = v[mi][r] + s;
                __bf16 hi = (__bf16)a;
                size_t pos = (size_t)(mi * 16 + quad * 4 + r) * 264 + o;
                Ad[pos] = hi;
                Ad[APLANE + pos] = (__bf16)(a - (float)hi);
            }
    }
}

__global__ __launch_bounds__(1024) void gin_fused(
    const float* __restrict__ ha,
    const __bf16* __restrict__ gW0a, const __bf16* __restrict__ gW0b,
    const __bf16* __restrict__ gW1a, const __bf16* __restrict__ gW1b,
    const __bf16* __restrict__ gW2a, const __bf16* __restrict__ gW2b,
    const float* __restrict__ b0a, const float* __restrict__ b0b,
    const float* __restrict__ b1a, const float* __restrict__ b1b,
    const float* __restrict__ b2a, const float* __restrict__ b2b,
    float* __restrict__ H3)
{
    const int b = blockIdx.x, tid = threadIdx.x;
    __shared__ __align__(16) __bf16 sA[2][2 * APLANE];
    __shared__ float sS[64];
    const float* hab = ha + (size_t)b * 2240;

    if (tid < 64) {
        float s = 0.f;
        if (tid < 35)
            for (int n = 0; n < 64; ++n) s += hab[n * 35 + tid];
        sS[tid] = s;
    }
    __syncthreads();
    for (int idx = tid; idx < 64 * 64; idx += 1024) {
        int n = idx >> 6, k = idx & 63;
        float a = (k < 35) ? hab[n * 35 + k] + sS[k] : 0.f;
        __bf16 hi = (__bf16)a;
        sA[0][n * 264 + k] = hi;
        sA[0][APLANE + n * 264 + k] = (__bf16)(a - (float)hi);
    }
    __syncthreads();

    gin_gemm_dev(sA[0], gW0a, 64,  16384, 256, b0a, 0, sA[1], nullptr); __syncthreads();
    gin_gemm_dev(sA[1], gW0b, 256, 65536, 256, b0b, 1, sA[0], nullptr); __syncthreads();
    gin_gemm_dev(sA[0], gW1a, 256, 65536, 256, b1a, 0, sA[1], nullptr); __syncthreads();
    gin_gemm_dev(sA[1], gW1b, 256, 65536, 256, b1b, 1, sA[0], nullptr); __syncthreads();
    gin_gemm_dev(sA[0], gW2a, 256, 16384, 35,  b2a, 0, sA[1], nullptr); __syncthreads();
    gin_gemm_dev(sA[1], gW2b, 64,  4096,  35,  b2b, 2, nullptr, H3 + (size_t)b * 2240);
}

// ---------------------------------------------------------------------------
// Classifier layer 1, fp32, K-split: grid (b=32, kc=16).
// ---------------------------------------------------------------------------
__global__ __launch_bounds__(256) void cls1_part_k(
    const float* __restrict__ H3, const float* __restrict__ w1,
    float* __restrict__ s1p)
{
    const int b  = blockIdx.x;
    const int kc = blockIdx.y;
    const int k0 = kc * 140;
    __shared__ float sH[140];
    const int tid = threadIdx.x;
    if (tid < 140) sH[tid] = H3[(size_t)b * 2240 + k0 + tid];
    __syncthreads();
    const int o = (tid >> 6) * 64 + (tid & 63);
    float a0 = 0.f, a1 = 0.f, a2 = 0.f, a3 = 0.f;
    const float* wr = w1 + (size_t)k0 * 256 + o;
    #pragma unroll
    for (int k = 0; k < 140; k += 4) {
        a0 = fmaf(sH[k],     wr[(size_t)k * 256],       a0);
        a1 = fmaf(sH[k + 1], wr[(size_t)(k + 1) * 256], a1);
        a2 = fmaf(sH[k + 2], wr[(size_t)(k + 2) * 256], a2);
        a3 = fmaf(sH[k + 3], wr[(size_t)(k + 3) * 256], a3);
    }
    s1p[((size_t)kc * 32 + b) * 256 + o] = a0 + a1 + a2 + a3;
}

// ---------------------------------------------------------------------------
// Classifier: reduce K-split partials (+bias, ELU), then layers 2-4 (fp32).
// ---------------------------------------------------------------------------
__global__ __launch_bounds__(256) void cls234_k(
    const float* __restrict__ s1p, const float* __restrict__ b1,
    const float* __restrict__ w2, const float* __restrict__ b2,
    const float* __restrict__ w3, const float* __restrict__ b3,
    const float* __restrict__ w4, const float* __restrict__ b4,
    float* __restrict__ out)
{
    const int b = blockIdx.x, tid = threadIdx.x;
    __shared__ float s1[256];
    __shared__ float part[4][64];
    __shared__ float s2[64];
    __shared__ float s3[16];
    {
        float acc = b1[tid];
        #pragma unroll
        for (int kc = 0; kc < 16; ++kc)
            acc += s1p[((size_t)kc * 32 + b) * 256 + tid];
        s1[tid] = elu_f(acc);
    }
    __syncthreads();
    {
        int kg = tid >> 6, o = tid & 63;
        float acc = 0.f;
        for (int k = kg * 64; k < kg * 64 + 64; ++k)
            acc = fmaf(s1[k], w2[k * 64 + o], acc);
        part[kg][o] = acc;
    }
    __syncthreads();
    if (tid < 64) {
        float acc = part[0][tid] + part[1][tid] + part[2][tid] + part[3][tid] + b2[tid];
        s2[tid] = elu_f(acc);
    }
    __syncthreads();
    if (tid < 16) {
        float acc = b3[tid];
        for (int k = 0; k < 64; ++k) acc = fmaf(s2[k], w3[k * 16 + tid], acc);
        s3[tid] = elu_f(acc);
    }
    __syncthreads();
    if (tid < 2) {
        float acc = b4[tid];
        for (int k = 0; k < 16; ++k) acc = fmaf(s3[k], w4[k * 2 + tid], acc);
        out[b * 2 + tid] = acc;
    }
}

// ---------------------------------------------------------------------------
extern "C" void kernel_launch(void* const* d_in, const int* in_sizes, int n_in,
                              void* d_out, int out_size, void* d_ws, size_t ws_size,
                              hipStream_t stream)
{
    const float* x     = (const float*)d_in[0];
    const float* w1    = (const float*)d_in[1];
    const float* b1    = (const float*)d_in[2];
    const float* bn1_g = (const float*)d_in[3];
    const float* bn1_b = (const float*)d_in[4];
    const float* bn1_m = (const float*)d_in[5];
    const float* bn1_v = (const float*)d_in[6];
    const float* w2    = (const float*)d_in[7];
    const float* b2    = (const float*)d_in[8];
    const float* bn2_g = (const float*)d_in[9];
    const float* bn2_b = (const float*)d_in[10];
    const float* bn2_m = (const float*)d_in[11];
    const float* bn2_v = (const float*)d_in[12];
    const float* w3    = (const float*)d_in[13];
    const float* b3    = (const float*)d_in[14];
    const float* w4    = (const float*)d_in[15];
    const float* b4    = (const float*)d_in[16];
    const float* attn_w = (const float*)d_in[17];
    const float* attn_b = (const float*)d_in[18];
    const float* attn_u = (const float*)d_in[19];
    const float* g0_w1 = (const float*)d_in[20];
    const float* g0_b1 = (const float*)d_in[21];
    const float* g0_w2 = (const float*)d_in[22];
    const float* g0_b2 = (const float*)d_in[23];
    const float* g1_w1 = (const float*)d_in[24];
    const float* g1_b1 = (const float*)d_in[25];
    const float* g1_w2 = (const float*)d_in[26];
    const float* g1_b2 = (const float*)d_in[27];
    const float* g2_w1 = (const float*)d_in[28];
    const float* g2_b1 = (const float*)d_in[29];
    const float* g2_w2 = (const float*)d_in[30];
    const float* g2_b2 = (const float*)d_in[31];
    const float* c_w1  = (const float*)d_in[32];
    const float* c_b1  = (const float*)d_in[33];
    const float* c_w2  = (const float*)d_in[34];
    const float* c_b2  = (const float*)d_in[35];
    const float* c_w3  = (const float*)d_in[36];
    const float* c_b3  = (const float*)d_in[37];
    const float* c_w4  = (const float*)d_in[38];
    const float* c_b4  = (const float*)d_in[39];
    float* out = (float*)d_out;

    char* ws = (char*)d_ws;
    __bf16* wT1  = (__bf16*)(ws + 0);
    __bf16* wT2  = (__bf16*)(ws + 163840);
    __bf16* wT3  = (__bf16*)(ws + 327680);
    __bf16* wT4  = (__bf16*)(ws + 376832);
    __bf16* h1   = (__bf16*)(ws + 425984);     // [512][192][64]
    __bf16* h2   = (__bf16*)(ws + 13008896);   // [512][87][64]
    __bf16* h3   = (__bf16*)(ws + 18710528);   // [512][82][64]
    __bf16* h4   = (__bf16*)(ws + 24084480);   // [512][35][64]
    float*  ha   = (float*)(ws + 26378240);    // [32][64][35]
    __bf16* gW0a = (__bf16*)(ws + 26664960);   // hi+lo [256][64]   65536 B
    __bf16* gW0b = (__bf16*)(ws + 26730496);   // hi+lo [256][256] 262144 B
    __bf16* gW1a = (__bf16*)(ws + 26992640);
    __bf16* gW1b = (__bf16*)(ws + 27254784);
    __bf16* gW2a = (__bf16*)(ws + 27516928);   // hi+lo [64][256]   65536 B
    __bf16* gW2b = (__bf16*)(ws + 27582464);   // hi+lo [64][64]    16384 B
    float*  H3   = (float*)(ws + 27598848);    // [32][2240]
    float*  s1p  = (float*)(ws + 27885568);    // [16][32][256] = 524288 B

    prep_weights<<<dim3(832), dim3(256), 0, stream>>>(w1, w2, w3, w4, wT1, wT2, wT3, wT4);
    prep_tr<<<dim3(57), dim3(256), 0, stream>>>(g0_w1, g0_w2, g1_w1, g1_w2, g2_w1, g2_w2,
                                                gW0a, gW0b, gW1a, gW1b, gW2a, gW2b);

    conv_mfma<20, 2, 1, true, 0, 1, 4, 400, 192, 2><<<dim3(512), dim3(256), 0, stream>>>(
        x, wT1, b1, bn1_g, bn1_b, bn1_m, bn1_v, h1);
    conv_mfma<20, 2, 0, true, 1, 1, 2, 192, 87, 2><<<dim3(512), dim3(128), 0, stream>>>(
        h1, wT2, b2, bn2_g, bn2_b, bn2_m, bn2_v, h2);
    conv_mfma<6, 1, 0, false, 1, 1, 2, 87, 82, 2><<<dim3(512), dim3(128), 0, stream>>>(
        h2, wT3, b3, nullptr, nullptr, nullptr, nullptr, h3);
    conv_mfma<6, 1, 0, false, 2, 2, 1, 40, 35, 2><<<dim3(256), dim3(128), 0, stream>>>(
        h3, wT4, b4, nullptr, nullptr, nullptr, nullptr, h4);

    attn_pool_k<<<dim3(2048), dim3(256), 0, stream>>>(h4, attn_w, attn_b, attn_u, ha);

    gin_fused<<<dim3(32), dim3(1024), 0, stream>>>(
        ha, gW0a, gW0b, gW1a, gW1b, gW2a, gW2b,
        g0_b1, g0_b2, g1_b1, g1_b2, g2_b1, g2_b2, H3);

    cls1_part_k<<<dim3(32, 16), dim3(256), 0, stream>>>(H3, c_w1, s1p);
    cls234_k<<<dim3(32), dim3(256), 0, stream>>>(s1p, c_b1, c_w2, c_b2, c_w3, c_b3,
                                                 c_w4, c_b4, out);
}

// Round 10
// 363.157 us; speedup vs baseline: 1.0430x; 1.0430x over previous
//
#include <hip/hip_runtime.h>
#include <math.h>

typedef __attribute__((ext_vector_type(8))) __bf16 bf16x8;
typedef __attribute__((ext_vector_type(4))) float f32x4;

__device__ __forceinline__ float elu_f(float v) {
    return v > 0.f ? v : (expf(v) - 1.f);
}

// ---------------------------------------------------------------------------
// Conv weight reorder: w[co][ci][K] fp32 -> wT[k][co][ci] bf16 (all 4 convs).
// ---------------------------------------------------------------------------
__global__ __launch_bounds__(256) void prep_weights(
    const float* __restrict__ w1, const float* __restrict__ w2,
    const float* __restrict__ w3, const float* __restrict__ w4,
    __bf16* __restrict__ t1, __bf16* __restrict__ t2,
    __bf16* __restrict__ t3, __bf16* __restrict__ t4)
{
    int idx = blockIdx.x * 256 + threadIdx.x;
    if (idx < 81920) {
        int k = idx / 4096, r = idx - k * 4096, co = r >> 6, ci = r & 63;
        t1[idx] = (__bf16)w1[(co * 64 + ci) * 20 + k];
    } else if (idx < 163840) {
        int j = idx - 81920;
        int k = j / 4096, r = j - k * 4096, co = r >> 6, ci = r & 63;
        t2[j] = (__bf16)w2[(co * 64 + ci) * 20 + k];
    } else if (idx < 188416) {
        int j = idx - 163840;
        int k = j / 4096, r = j - k * 4096, co = r >> 6, ci = r & 63;
        t3[j] = (__bf16)w3[(co * 64 + ci) * 6 + k];
    } else if (idx < 212992) {
        int j = idx - 188416;
        int k = j / 4096, r = j - k * 4096, co = r >> 6, ci = r & 63;
        t4[j] = (__bf16)w4[(co * 64 + ci) * 6 + k];
    }
}

// ---------------------------------------------------------------------------
// Tiled transpose+convert with hi/lo split for GIN weights. 57 blocks.
// ---------------------------------------------------------------------------
__global__ __launch_bounds__(256) void prep_tr(
    const float* __restrict__ g0w1, const float* __restrict__ g0w2,
    const float* __restrict__ g1w1, const float* __restrict__ g1w2,
    const float* __restrict__ g2w1, const float* __restrict__ g2w2,
    __bf16* __restrict__ d0, __bf16* __restrict__ d1, __bf16* __restrict__ d2,
    __bf16* __restrict__ d3, __bf16* __restrict__ d4, __bf16* __restrict__ d5)
{
    int bid = blockIdx.x;
    const float* src; __bf16* dst; int K, O, Kpad, Opad, tile;
    if (bid < 4)       { src = g0w1; dst = d0; K = 35;   O = 256; Kpad = 64;   Opad = 256; tile = bid; }
    else if (bid < 20) { src = g0w2; dst = d1; K = 256;  O = 256; Kpad = 256;  Opad = 256; tile = bid - 4; }
    else if (bid < 36) { src = g1w1; dst = d2; K = 256;  O = 256; Kpad = 256;  Opad = 256; tile = bid - 20; }
    else if (bid < 52) { src = g1w2; dst = d3; K = 256;  O = 256; Kpad = 256;  Opad = 256; tile = bid - 36; }
    else if (bid < 56) { src = g2w1; dst = d4; K = 256;  O = 35;  Kpad = 256;  Opad = 64;  tile = bid - 52; }
    else               { src = g2w2; dst = d5; K = 35;   O = 35;  Kpad = 64;   Opad = 64;  tile = 0; }
    int ktiles = Kpad >> 6;
    int ot = tile / ktiles, kt = tile - ot * ktiles;
    int k0 = kt * 64, o0 = ot * 64;
    size_t LOFF = (size_t)Opad * Kpad;
    __shared__ float tl[64][68];
    int c = threadIdx.x & 63, rr = threadIdx.x >> 6;
    #pragma unroll
    for (int it = 0; it < 16; ++it) {
        int r = rr + it * 4;
        int kk = k0 + r, oo = o0 + c;
        tl[r][c] = (kk < K && oo < O) ? src[(size_t)kk * O + oo] : 0.f;
    }
    __syncthreads();
    #pragma unroll
    for (int it = 0; it < 16; ++it) {
        int r = rr + it * 4;
        float v = tl[c][r];
        __bf16 hi = (__bf16)v;
        float lo = v - (float)hi;
        size_t pos = (size_t)(o0 + r) * Kpad + k0 + c;
        dst[pos] = hi;
        dst[LOFF + pos] = (__bf16)lo;
    }
}

// ---------------------------------------------------------------------------
// MFMA conv1d, Cin=Cout=64. Output [n][t][64co] bf16.
// v4: barrier-free K-loop. Input staged to LDS once (t-inner map: coalesced
// global reads). Weights are NOT staged in LDS: each wave double-buffers its
// 8 B-fragments per tap in registers, prefetching tap k+1 from L2-hot wT
// while MFMAing tap k (AITER-style interleave). Zero barriers after staging.
// ---------------------------------------------------------------------------
template<int K, int STRIDE, int PAD, bool DO_BN, int IMODE,
         int NPB, int TPN, int LIN, int LOUT>
__global__ __launch_bounds__(NPB * TPN * 64, 2) void conv_mfma(
    const void* __restrict__ xin, const __bf16* __restrict__ wT,
    const float* __restrict__ bias,
    const float* __restrict__ bn_g, const float* __restrict__ bn_b,
    const float* __restrict__ bn_m, const float* __restrict__ bn_v,
    __bf16* __restrict__ y)
{
    constexpr int THREADS = NPB * TPN * 64;
    constexpr int TBLK  = TPN * 48;
    constexpr int VSPAN = STRIDE * (TBLK - 1) + K;
    constexpr int NBUF  = (STRIDE == 2) ? 2 : 1;
    constexpr int ROWS  = (VSPAN + NBUF - 1) / NBUF;
    __shared__ __align__(16) __bf16 sx[NPB * NBUF * ROWS * 72];

    const int tid = threadIdx.x;
    const int nb  = blockIdx.x * NPB;

    if constexpr (IMODE == 0) {
        // fp32 [ci][LIN] -> bf16 [v(parity)][ci]; t-inner: coalesced reads.
        const float* xg = (const float*)xin + (size_t)nb * 64 * LIN;
        constexpr int NZROWS = PAD + (VSPAN - LIN - PAD);
        if (tid < NZROWS * 64) {
            int zr = tid >> 6;
            int v = (zr < PAD) ? zr : (LIN + PAD + zr - PAD);
            sx[((v & (NBUF - 1)) * ROWS + (v >> (NBUF - 1))) * 72 + (tid & 63)] = (__bf16)0.f;
        }
        constexpr int J4 = LIN / 4;
        constexpr int NCH = 64 * J4;
        constexpr int ITER = NCH / THREADS;
        #pragma unroll
        for (int it = 0; it < ITER; ++it) {
            int idx = it * THREADS + tid;
            int ci = idx / J4, j = idx - ci * J4;
            float4 f = *(const float4*)(xg + (size_t)ci * LIN + 4 * j);
            #pragma unroll
            for (int e = 0; e < 4; ++e) {
                int v = 4 * j + e + PAD;
                sx[((v & (NBUF - 1)) * ROWS + (v >> (NBUF - 1))) * 72 + ci] =
                    (__bf16)((e == 0) ? f.x : (e == 1) ? f.y : (e == 2) ? f.z : f.w);
            }
        }
    } else {
        const __bf16* xg = (const __bf16*)xin;
        constexpr int NSTG = NPB * VSPAN * 8;
        constexpr int ITER = (NSTG + THREADS - 1) / THREADS;
        #pragma unroll
        for (int it = 0; it < ITER; ++it) {
            int idx = it * THREADS + tid;
            if (idx < NSTG) {
                int n_l = idx / (VSPAN * 8);
                int r   = idx - n_l * (VSPAN * 8);
                int v = r >> 3, c8 = (r & 7) * 8;
                int buf = (STRIDE == 2) ? (v & 1) : 0;
                int row = (STRIDE == 2) ? (v >> 1) : v;
                __bf16* dst = sx + ((size_t)(n_l * NBUF + buf) * ROWS + row) * 72 + c8;
                if constexpr (IMODE == 1) {
                    if (v < LIN) {
                        const __bf16* src = xg + (((size_t)(nb + n_l) * LIN + v) * 64 + c8);
                        *(uint4*)dst = *(const uint4*)src;
                    } else {
                        #pragma unroll
                        for (int e = 0; e < 8; ++e) dst[e] = (__bf16)0.f;
                    }
                } else {
                    if (v < LIN) {
                        const __bf16* s0 = xg + (((size_t)(nb + n_l) * 82 + 2 * v) * 64 + c8);
                        #pragma unroll
                        for (int e = 0; e < 8; ++e)
                            dst[e] = (__bf16)(((float)s0[e] + (float)s0[64 + e] +
                                               (float)s0[128 + e]) * (1.f / 3.f));
                    } else {
                        #pragma unroll
                        for (int e = 0; e < 8; ++e) dst[e] = (__bf16)0.f;
                    }
                }
            }
        }
    }
    __syncthreads();   // the only barrier

    const int wave = tid >> 6, lane = tid & 63;
    const int n_l  = wave / TPN, tile = wave - n_l * TPN;
    const int m    = lane & 15, quad = lane >> 4;
    const __bf16* sxn = sx + (size_t)n_l * NBUF * ROWS * 72;

    f32x4 acc[3][4];
    #pragma unroll
    for (int mi = 0; mi < 3; ++mi)
        #pragma unroll
        for (int nj = 0; nj < 4; ++nj)
            acc[mi][nj] = (f32x4){0.f, 0.f, 0.f, 0.f};

    // register double-buffered weight fragments: [buf][nj*2+s]
    const __bf16* wlane = wT + (size_t)m * 64 + quad * 8;
    bf16x8 wreg[2][8];
    #pragma unroll
    for (int nj = 0; nj < 4; ++nj)
        #pragma unroll
        for (int s = 0; s < 2; ++s)
            wreg[0][nj * 2 + s] = *(const bf16x8*)(wlane + nj * 1024 + s * 32);

    #pragma unroll
    for (int kp = 0; kp < K; ++kp) {
        const int cur = kp & 1, nxt = cur ^ 1;
        if (kp + 1 < K) {
            const __bf16* wnext = wlane + (size_t)(kp + 1) * 4096;
            #pragma unroll
            for (int nj = 0; nj < 4; ++nj)
                #pragma unroll
                for (int s = 0; s < 2; ++s)
                    wreg[nxt][nj * 2 + s] = *(const bf16x8*)(wnext + nj * 1024 + s * 32);
        }
        const int buf    = (STRIDE == 2) ? (kp & 1) : 0;
        const int rowoff = (STRIDE == 2) ? (kp >> 1) : kp;
        const __bf16* abase = sxn + ((size_t)buf * ROWS + tile * 48 + m + rowoff) * 72;
        #pragma unroll
        for (int s = 0; s < 2; ++s) {
            bf16x8 af[3];
            #pragma unroll
            for (int mi = 0; mi < 3; ++mi)
                af[mi] = *(const bf16x8*)(abase + mi * (16 * 72) + s * 32 + quad * 8);
            #pragma unroll
            for (int mi = 0; mi < 3; ++mi)
                #pragma unroll
                for (int nj = 0; nj < 4; ++nj)
                    acc[mi][nj] = __builtin_amdgcn_mfma_f32_16x16x32_bf16(
                        af[mi], wreg[cur][nj * 2 + s], acc[mi][nj], 0, 0, 0);
        }
    }

    #pragma unroll
    for (int nj = 0; nj < 4; ++nj) {
        const int co = nj * 16 + m;
        const float bi = bias[co];
        float scale = 1.f, shift = 0.f;
        if constexpr (DO_BN) {
            float inv = bn_g[co] / sqrtf(bn_v[co] + 1e-5f);
            scale = inv; shift = bn_b[co] - bn_m[co] * inv;
        }
        #pragma unroll
        for (int mi = 0; mi < 3; ++mi) {
            #pragma unroll
            for (int r = 0; r < 4; ++r) {
                int t = tile * 48 + mi * 16 + quad * 4 + r;
                if (t < LOUT) {
                    float v = acc[mi][nj][r] + bi;
                    v = elu_f(v);
                    if constexpr (DO_BN) v = v * scale + shift;
                    y[((size_t)(nb + n_l) * LOUT + t) * 64 + co] = (__bf16)v;
                }
            }
        }
    }
}

// ---------------------------------------------------------------------------
// Attention pooling over crop dim. One block per (b,c). h: [512][35][64] bf16.
// ---------------------------------------------------------------------------
__global__ __launch_bounds__(256) void attn_pool_k(
    const __bf16* __restrict__ h, const float* __restrict__ W,
    const float* __restrict__ ab, const float* __restrict__ u,
    float* __restrict__ out)
{
    const int b = blockIdx.x >> 6;
    const int c = blockIdx.x & 63;
    __shared__ float sh[16 * 35];
    __shared__ float slog[16];
    __shared__ float sred[4];
    __shared__ float salpha[16];
    const int tid = threadIdx.x;
    for (int idx = tid; idx < 16 * 35; idx += 256) {
        int s = idx / 35, hh = idx - s * 35;
        sh[idx] = (float)h[((size_t)(b * 16 + s) * 35 + hh) * 64 + c];
    }
    __syncthreads();
    float Wc[35];
    #pragma unroll
    for (int k = 0; k < 35; ++k) Wc[k] = W[k * 256 + tid];
    const float myb = ab[tid], myu = u[tid];
    for (int s = 0; s < 16; ++s) {
        float dot = myb;
        #pragma unroll
        for (int k = 0; k < 35; ++k) dot = fmaf(sh[s * 35 + k], Wc[k], dot);
        float val = tanhf(dot) * myu;
        #pragma unroll
        for (int off = 32; off > 0; off >>= 1) val += __shfl_down(val, off, 64);
        if ((tid & 63) == 0) sred[tid >> 6] = val;
        __syncthreads();
        if (tid == 0) slog[s] = sred[0] + sred[1] + sred[2] + sred[3];
        __syncthreads();
    }
    if (tid == 0) {
        float mx = slog[0];
        for (int s = 1; s < 16; ++s) mx = fmaxf(mx, slog[s]);
        float sum = 0.f, e[16];
        for (int s = 0; s < 16; ++s) { e[s] = expf(slog[s] - mx); sum += e[s]; }
        float inv = 1.f / sum;
        for (int s = 0; s < 16; ++s) salpha[s] = e[s] * inv;
    }
    __syncthreads();
    if (tid < 35) {
        float acc = 0.f;
        for (int s = 0; s < 16; ++s) acc = fmaf(sh[s * 35 + tid], salpha[s], acc);
        out[((size_t)(b * 64 + c)) * 35 + tid] = elu_f(acc);
    }
}

// ---------------------------------------------------------------------------
// Fused GIN stack, split-bf16 (hi/lo). 512 threads = 8 waves; each wave owns
// a 32-wide output strip (2 nj fragments): 2x latency hiding of 4-wave, half
// the redundant A-traffic of the 16-wave variant.
// ---------------------------------------------------------------------------
#define APLANE (64 * 264)

__device__ __forceinline__ void gin_gemm_dev(
    const __bf16* As,                 // hi plane; lo at As+APLANE
    const __bf16* __restrict__ Wg, int Kpad, int wlo, int Kout,
    const float* __restrict__ bias,
    int mode,                 // 0: relu->A   1: relu, +colsum ->A   2: raw->global
    __bf16* Ad, float* __restrict__ outg)
{
    const int lane = threadIdx.x & 63;
    const int wave = threadIdx.x >> 6;      // 0..7
    const int o0 = wave * 32;
    if (o0 >= ((Kout + 63) & ~63)) return;
    const int m = lane & 15, quad = lane >> 4;

    f32x4 acc[4][2];
    #pragma unroll
    for (int mi = 0; mi < 4; ++mi)
        #pragma unroll
        for (int nj = 0; nj < 2; ++nj)
            acc[mi][nj] = (f32x4){0.f, 0.f, 0.f, 0.f};

    for (int k0 = 0; k0 < Kpad; k0 += 32) {
        bf16x8 ah[4], al[4], bh[2], bl[2];
        #pragma unroll
        for (int mi = 0; mi < 4; ++mi) {
            const __bf16* ap = As + (size_t)(mi * 16 + m) * 264 + k0 + quad * 8;
            ah[mi] = *(const bf16x8*)ap;
            al[mi] = *(const bf16x8*)(ap + APLANE);
        }
        #pragma unroll
        for (int nj = 0; nj < 2; ++nj) {
            const __bf16* wp = Wg + (size_t)(o0 + nj * 16 + m) * Kpad + k0 + quad * 8;
            bh[nj] = *(const bf16x8*)wp;
            bl[nj] = *(const bf16x8*)(wp + wlo);
        }
        #pragma unroll
        for (int mi = 0; mi < 4; ++mi)
            #pragma unroll
            for (int nj = 0; nj < 2; ++nj) {
                acc[mi][nj] = __builtin_amdgcn_mfma_f32_16x16x32_bf16(
                    al[mi], bh[nj], acc[mi][nj], 0, 0, 0);
                acc[mi][nj] = __builtin_amdgcn_mfma_f32_16x16x32_bf16(
                    ah[mi], bl[nj], acc[mi][nj], 0, 0, 0);
                acc[mi][nj] = __builtin_amdgcn_mfma_f32_16x16x32_bf16(
                    ah[mi], bh[nj], acc[mi][nj], 0, 0, 0);
            }
    }

    #pragma unroll
    for (int nj = 0; nj < 2; ++nj) {
        const int o = o0 + nj * 16 + m;
        const bool ovalid = (o < Kout);
        const float bi = ovalid ? bias[o] : 0.f;
        float v[4][4];
        #pragma unroll
        for (int mi = 0; mi < 4; ++mi)
            #pragma unroll
            for (int r = 0; r < 4; ++r)
                v[mi][r] = acc[mi][nj][r] + bi;
        if (mode == 2) {
            if (ovalid) {
                #pragma unroll
                for (int mi = 0; mi < 4; ++mi)
                    #pragma unroll
                    for (int r = 0; r < 4; ++r)
                        outg[(size_t)(mi * 16 + quad * 4 + r) * Kout + o] = v[mi][r];
            }
        } else {
            float s = 0.f;
            #pragma unroll
            for (int mi = 0; mi < 4; ++mi)
                #pragma unroll
                for (int r = 0; r < 4; ++r) {
                    float rv = ovalid ? fmaxf(v[mi][r], 0.f) : 0.f;
                    v[mi][r] = rv;
                    s += rv;
                }
            if (mode == 1) {
                s += __shfl_xor(s, 16, 64);
                s += __shfl_xor(s, 32, 64);
            } else {
                s = 0.f;
            }
            #pragma unroll
            for (int mi = 0; mi < 4; ++mi)
                #pragma unroll
                for (int r = 0; r < 4; ++r) {
                    float a = v[mi][r] + s;
                    __bf16 hi = (__bf16)a;
                    size_t pos = (size_t)(mi * 16 + quad * 4 + r) * 264 + o;
                    Ad[pos] = hi;
                    Ad[APLANE + pos] = (__bf16)(a - (float)hi);
                }
        }
    }
}

__global__ __launch_bounds__(512) void gin_fused(
    const float* __restrict__ ha,
    const __bf16* __restrict__ gW0a, const __bf16* __restrict__ gW0b,
    const __bf16* __restrict__ gW1a, const __bf16* __restrict__ gW1b,
    const __bf16* __restrict__ gW2a, const __bf16* __restrict__ gW2b,
    const float* __restrict__ b0a, const float* __restrict__ b0b,
    const float* __restrict__ b1a, const float* __restrict__ b1b,
    const float* __restrict__ b2a, const float* __restrict__ b2b,
    float* __restrict__ H3)
{
    const int b = blockIdx.x, tid = threadIdx.x;
    __shared__ __align__(16) __bf16 sA[2][2 * APLANE];
    __shared__ float sS[64];
    const float* hab = ha + (size_t)b * 2240;

    if (tid < 64) {
        float s = 0.f;
        if (tid < 35)
            for (int n = 0; n < 64; ++n) s += hab[n * 35 + tid];
        sS[tid] = s;
    }
    __syncthreads();
    for (int idx = tid; idx < 64 * 64; idx += 512) {
        int n = idx >> 6, k = idx & 63;
        float a = (k < 35) ? hab[n * 35 + k] + sS[k] : 0.f;
        __bf16 hi = (__bf16)a;
        sA[0][n * 264 + k] = hi;
        sA[0][APLANE + n * 264 + k] = (__bf16)(a - (float)hi);
    }
    __syncthreads();

    gin_gemm_dev(sA[0], gW0a, 64,  16384, 256, b0a, 0, sA[1], nullptr); __syncthreads();
    gin_gemm_dev(sA[1], gW0b, 256, 65536, 256, b0b, 1, sA[0], nullptr); __syncthreads();
    gin_gemm_dev(sA[0], gW1a, 256, 65536, 256, b1a, 0, sA[1], nullptr); __syncthreads();
    gin_gemm_dev(sA[1], gW1b, 256, 65536, 256, b1b, 1, sA[0], nullptr); __syncthreads();
    gin_gemm_dev(sA[0], gW2a, 256, 16384, 35,  b2a, 0, sA[1], nullptr); __syncthreads();
    gin_gemm_dev(sA[1], gW2b, 64,  4096,  35,  b2b, 2, nullptr, H3 + (size_t)b * 2240);
}

// ---------------------------------------------------------------------------
// Classifier layer 1, fp32, K-split: grid (b=32, kc=16).
// ---------------------------------------------------------------------------
__global__ __launch_bounds__(256) void cls1_part_k(
    const float* __restrict__ H3, const float* __restrict__ w1,
    float* __restrict__ s1p)
{
    const int b  = blockIdx.x;
    const int kc = blockIdx.y;
    const int k0 = kc * 140;
    __shared__ float sH[140];
    const int tid = threadIdx.x;
    if (tid < 140) sH[tid] = H3[(size_t)b * 2240 + k0 + tid];
    __syncthreads();
    const int o = (tid >> 6) * 64 + (tid & 63);
    float a0 = 0.f, a1 = 0.f, a2 = 0.f, a3 = 0.f;
    const float* wr = w1 + (size_t)k0 * 256 + o;
    #pragma unroll
    for (int k = 0; k < 140; k += 4) {
        a0 = fmaf(sH[k],     wr[(size_t)k * 256],       a0);
        a1 = fmaf(sH[k + 1], wr[(size_t)(k + 1) * 256], a1);
        a2 = fmaf(sH[k + 2], wr[(size_t)(k + 2) * 256], a2);
        a3 = fmaf(sH[k + 3], wr[(size_t)(k + 3) * 256], a3);
    }
    s1p[((size_t)kc * 32 + b) * 256 + o] = a0 + a1 + a2 + a3;
}

// ---------------------------------------------------------------------------
// Classifier: reduce K-split partials (+bias, ELU), then layers 2-4 (fp32).
// ---------------------------------------------------------------------------
__global__ __launch_bounds__(256) void cls234_k(
    const float* __restrict__ s1p, const float* __restrict__ b1,
    const float* __restrict__ w2, const float* __restrict__ b2,
    const float* __restrict__ w3, const float* __restrict__ b3,
    const float* __restrict__ w4, const float* __restrict__ b4,
    float* __restrict__ out)
{
    const int b = blockIdx.x, tid = threadIdx.x;
    __shared__ float s1[256];
    __shared__ float part[4][64];
    __shared__ float s2[64];
    __shared__ float s3[16];
    {
        float acc = b1[tid];
        #pragma unroll
        for (int kc = 0; kc < 16; ++kc)
            acc += s1p[((size_t)kc * 32 + b) * 256 + tid];
        s1[tid] = elu_f(acc);
    }
    __syncthreads();
    {
        int kg = tid >> 6, o = tid & 63;
        float acc = 0.f;
        for (int k = kg * 64; k < kg * 64 + 64; ++k)
            acc = fmaf(s1[k], w2[k * 64 + o], acc);
        part[kg][o] = acc;
    }
    __syncthreads();
    if (tid < 64) {
        float acc = part[0][tid] + part[1][tid] + part[2][tid] + part[3][tid] + b2[tid];
        s2[tid] = elu_f(acc);
    }
    __syncthreads();
    if (tid < 16) {
        float acc = b3[tid];
        for (int k = 0; k < 64; ++k) acc = fmaf(s2[k], w3[k * 16 + tid], acc);
        s3[tid] = elu_f(acc);
    }
    __syncthreads();
    if (tid < 2) {
        float acc = b4[tid];
        for (int k = 0; k < 16; ++k) acc = fmaf(s3[k], w4[k * 2 + tid], acc);
        out[b * 2 + tid] = acc;
    }
}

// ---------------------------------------------------------------------------
extern "C" void kernel_launch(void* const* d_in, const int* in_sizes, int n_in,
                              void* d_out, int out_size, void* d_ws, size_t ws_size,
                              hipStream_t stream)
{
    const float* x     = (const float*)d_in[0];
    const float* w1    = (const float*)d_in[1];
    const float* b1    = (const float*)d_in[2];
    const float* bn1_g = (const float*)d_in[3];
    const float* bn1_b = (const float*)d_in[4];
    const float* bn1_m = (const float*)d_in[5];
    const float* bn1_v = (const float*)d_in[6];
    const float* w2    = (const float*)d_in[7];
    const float* b2    = (const float*)d_in[8];
    const float* bn2_g = (const float*)d_in[9];
    const float* bn2_b = (const float*)d_in[10];
    const float* bn2_m = (const float*)d_in[11];
    const float* bn2_v = (const float*)d_in[12];
    const float* w3    = (const float*)d_in[13];
    const float* b3    = (const float*)d_in[14];
    const float* w4    = (const float*)d_in[15];
    const float* b4    = (const float*)d_in[16];
    const float* attn_w = (const float*)d_in[17];
    const float* attn_b = (const float*)d_in[18];
    const float* attn_u = (const float*)d_in[19];
    const float* g0_w1 = (const float*)d_in[20];
    const float* g0_b1 = (const float*)d_in[21];
    const float* g0_w2 = (const float*)d_in[22];
    const float* g0_b2 = (const float*)d_in[23];
    const float* g1_w1 = (const float*)d_in[24];
    const float* g1_b1 = (const float*)d_in[25];
    const float* g1_w2 = (const float*)d_in[26];
    const float* g1_b2 = (const float*)d_in[27];
    const float* g2_w1 = (const float*)d_in[28];
    const float* g2_b1 = (const float*)d_in[29];
    const float* g2_w2 = (const float*)d_in[30];
    const float* g2_b2 = (const float*)d_in[31];
    const float* c_w1  = (const float*)d_in[32];
    const float* c_b1  = (const float*)d_in[33];
    const float* c_w2  = (const float*)d_in[34];
    const float* c_b2  = (const float*)d_in[35];
    const float* c_w3  = (const float*)d_in[36];
    const float* c_b3  = (const float*)d_in[37];
    const float* c_w4  = (const float*)d_in[38];
    const float* c_b4  = (const float*)d_in[39];
    float* out = (float*)d_out;

    char* ws = (char*)d_ws;
    __bf16* wT1  = (__bf16*)(ws + 0);
    __bf16* wT2  = (__bf16*)(ws + 163840);
    __bf16* wT3  = (__bf16*)(ws + 327680);
    __bf16* wT4  = (__bf16*)(ws + 376832);
    __bf16* h1   = (__bf16*)(ws + 425984);     // [512][192][64]
    __bf16* h2   = (__bf16*)(ws + 13008896);   // [512][87][64]
    __bf16* h3   = (__bf16*)(ws + 18710528);   // [512][82][64]
    __bf16* h4   = (__bf16*)(ws + 24084480);   // [512][35][64]
    float*  ha   = (float*)(ws + 26378240);    // [32][64][35]
    __bf16* gW0a = (__bf16*)(ws + 26664960);   // hi+lo [256][64]   65536 B
    __bf16* gW0b = (__bf16*)(ws + 26730496);   // hi+lo [256][256] 262144 B
    __bf16* gW1a = (__bf16*)(ws + 26992640);
    __bf16* gW1b = (__bf16*)(ws + 27254784);
    __bf16* gW2a = (__bf16*)(ws + 27516928);   // hi+lo [64][256]   65536 B
    __bf16* gW2b = (__bf16*)(ws + 27582464);   // hi+lo [64][64]    16384 B
    float*  H3   = (float*)(ws + 27598848);    // [32][2240]
    float*  s1p  = (float*)(ws + 27885568);    // [16][32][256] = 524288 B

    prep_weights<<<dim3(832), dim3(256), 0, stream>>>(w1, w2, w3, w4, wT1, wT2, wT3, wT4);
    prep_tr<<<dim3(57), dim3(256), 0, stream>>>(g0_w1, g0_w2, g1_w1, g1_w2, g2_w1, g2_w2,
                                                gW0a, gW0b, gW1a, gW1b, gW2a, gW2b);

    // CNN stack: barrier-free K-loops, register-pipelined weights
    conv_mfma<20, 2, 1, true, 0, 1, 4, 400, 192><<<dim3(512), dim3(256), 0, stream>>>(
        x, wT1, b1, bn1_g, bn1_b, bn1_m, bn1_v, h1);
    conv_mfma<20, 2, 0, true, 1, 1, 2, 192, 87><<<dim3(512), dim3(128), 0, stream>>>(
        h1, wT2, b2, bn2_g, bn2_b, bn2_m, bn2_v, h2);
    conv_mfma<6, 1, 0, false, 1, 1, 2, 87, 82><<<dim3(512), dim3(128), 0, stream>>>(
        h2, wT3, b3, nullptr, nullptr, nullptr, nullptr, h3);
    conv_mfma<6, 1, 0, false, 2, 2, 1, 40, 35><<<dim3(256), dim3(128), 0, stream>>>(
        h3, wT4, b4, nullptr, nullptr, nullptr, nullptr, h4);

    attn_pool_k<<<dim3(2048), dim3(256), 0, stream>>>(h4, attn_w, attn_b, attn_u, ha);

    gin_fused<<<dim3(32), dim3(512), 0, stream>>>(
        ha, gW0a, gW0b, gW1a, gW1b, gW2a, gW2b,
        g0_b1, g0_b2, g1_b1, g1_b2, g2_b1, g2_b2, H3);

    cls1_part_k<<<dim3(32, 16), dim3(256), 0, stream>>>(H3, c_w1, s1p);
    cls234_k<<<dim3(32), dim3(256), 0, stream>>>(s1p, c_b1, c_w2, c_b2, c_w3, c_b3,
                                                 c_w4, c_b4, out);
}

// Round 11
// 322.654 us; speedup vs baseline: 1.1740x; 1.1255x over previous
//
#include <hip/hip_runtime.h>
#include <math.h>

typedef __attribute__((ext_vector_type(8))) __bf16 bf16x8;
typedef __attribute__((ext_vector_type(4))) float f32x4;

__device__ __forceinline__ float elu_f(float v) {
    return v > 0.f ? v : (expf(v) - 1.f);
}

// ---------------------------------------------------------------------------
// Conv weight reorder: w[co][ci][K] fp32 -> wT[k][co][ci] bf16 (all 4 convs).
// ---------------------------------------------------------------------------
__global__ __launch_bounds__(256) void prep_weights(
    const float* __restrict__ w1, const float* __restrict__ w2,
    const float* __restrict__ w3, const float* __restrict__ w4,
    __bf16* __restrict__ t1, __bf16* __restrict__ t2,
    __bf16* __restrict__ t3, __bf16* __restrict__ t4)
{
    int idx = blockIdx.x * 256 + threadIdx.x;
    if (idx < 81920) {
        int k = idx / 4096, r = idx - k * 4096, co = r >> 6, ci = r & 63;
        t1[idx] = (__bf16)w1[(co * 64 + ci) * 20 + k];
    } else if (idx < 163840) {
        int j = idx - 81920;
        int k = j / 4096, r = j - k * 4096, co = r >> 6, ci = r & 63;
        t2[j] = (__bf16)w2[(co * 64 + ci) * 20 + k];
    } else if (idx < 188416) {
        int j = idx - 163840;
        int k = j / 4096, r = j - k * 4096, co = r >> 6, ci = r & 63;
        t3[j] = (__bf16)w3[(co * 64 + ci) * 6 + k];
    } else if (idx < 212992) {
        int j = idx - 188416;
        int k = j / 4096, r = j - k * 4096, co = r >> 6, ci = r & 63;
        t4[j] = (__bf16)w4[(co * 64 + ci) * 6 + k];
    }
}

// ---------------------------------------------------------------------------
// Tiled transpose+convert with hi/lo split for GIN weights. 57 blocks.
// ---------------------------------------------------------------------------
__global__ __launch_bounds__(256) void prep_tr(
    const float* __restrict__ g0w1, const float* __restrict__ g0w2,
    const float* __restrict__ g1w1, const float* __restrict__ g1w2,
    const float* __restrict__ g2w1, const float* __restrict__ g2w2,
    __bf16* __restrict__ d0, __bf16* __restrict__ d1, __bf16* __restrict__ d2,
    __bf16* __restrict__ d3, __bf16* __restrict__ d4, __bf16* __restrict__ d5)
{
    int bid = blockIdx.x;
    const float* src; __bf16* dst; int K, O, Kpad, Opad, tile;
    if (bid < 4)       { src = g0w1; dst = d0; K = 35;   O = 256; Kpad = 64;   Opad = 256; tile = bid; }
    else if (bid < 20) { src = g0w2; dst = d1; K = 256;  O = 256; Kpad = 256;  Opad = 256; tile = bid - 4; }
    else if (bid < 36) { src = g1w1; dst = d2; K = 256;  O = 256; Kpad = 256;  Opad = 256; tile = bid - 20; }
    else if (bid < 52) { src = g1w2; dst = d3; K = 256;  O = 256; Kpad = 256;  Opad = 256; tile = bid - 36; }
    else if (bid < 56) { src = g2w1; dst = d4; K = 256;  O = 35;  Kpad = 256;  Opad = 64;  tile = bid - 52; }
    else               { src = g2w2; dst = d5; K = 35;   O = 35;  Kpad = 64;   Opad = 64;  tile = 0; }
    int ktiles = Kpad >> 6;
    int ot = tile / ktiles, kt = tile - ot * ktiles;
    int k0 = kt * 64, o0 = ot * 64;
    size_t LOFF = (size_t)Opad * Kpad;
    __shared__ float tl[64][68];
    int c = threadIdx.x & 63, rr = threadIdx.x >> 6;
    #pragma unroll
    for (int it = 0; it < 16; ++it) {
        int r = rr + it * 4;
        int kk = k0 + r, oo = o0 + c;
        tl[r][c] = (kk < K && oo < O) ? src[(size_t)kk * O + oo] : 0.f;
    }
    __syncthreads();
    #pragma unroll
    for (int it = 0; it < 16; ++it) {
        int r = rr + it * 4;
        float v = tl[c][r];
        __bf16 hi = (__bf16)v;
        float lo = v - (float)hi;
        size_t pos = (size_t)(o0 + r) * Kpad + k0 + c;
        dst[pos] = hi;
        dst[LOFF + pos] = (__bf16)lo;
    }
}

// ---------------------------------------------------------------------------
// MFMA conv1d, Cin=Cout=64. Output [n][t][64co] bf16. Pure-LDS K-loop.
// Round-8 proven structure: KCHUNK=2 LDS weight staging, t-inner IMODE0.
// ---------------------------------------------------------------------------
template<int K, int STRIDE, int PAD, bool DO_BN, int IMODE,
         int NPB, int TPN, int LIN, int LOUT, int KCHUNK>
__global__ __launch_bounds__(NPB * TPN * 64, 2) void conv_mfma(
    const void* __restrict__ xin, const __bf16* __restrict__ wT,
    const float* __restrict__ bias,
    const float* __restrict__ bn_g, const float* __restrict__ bn_b,
    const float* __restrict__ bn_m, const float* __restrict__ bn_v,
    __bf16* __restrict__ y)
{
    constexpr int THREADS = NPB * TPN * 64;
    constexpr int TBLK  = TPN * 48;
    constexpr int VSPAN = STRIDE * (TBLK - 1) + K;
    constexpr int NBUF  = (STRIDE == 2) ? 2 : 1;
    constexpr int ROWS  = (VSPAN + NBUF - 1) / NBUF;
    __shared__ __align__(16) __bf16 sx[NPB * NBUF * ROWS * 72];
    __shared__ __align__(16) __bf16 sw[KCHUNK * 64 * 72];

    const int tid = threadIdx.x;
    const int nb  = blockIdx.x * NPB;

    if constexpr (IMODE == 0) {
        const float* xg = (const float*)xin + (size_t)nb * 64 * LIN;
        constexpr int NZROWS = PAD + (VSPAN - LIN - PAD);
        if (tid < NZROWS * 64) {
            int zr = tid >> 6;
            int v = (zr < PAD) ? zr : (LIN + PAD + zr - PAD);
            sx[((v & (NBUF - 1)) * ROWS + (v >> (NBUF - 1))) * 72 + (tid & 63)] = (__bf16)0.f;
        }
        constexpr int J4 = LIN / 4;
        constexpr int NCH = 64 * J4;
        constexpr int ITER = NCH / THREADS;
        #pragma unroll
        for (int it = 0; it < ITER; ++it) {
            int idx = it * THREADS + tid;
            int ci = idx / J4, j = idx - ci * J4;
            float4 f = *(const float4*)(xg + (size_t)ci * LIN + 4 * j);
            #pragma unroll
            for (int e = 0; e < 4; ++e) {
                int v = 4 * j + e + PAD;
                sx[((v & (NBUF - 1)) * ROWS + (v >> (NBUF - 1))) * 72 + ci] =
                    (__bf16)((e == 0) ? f.x : (e == 1) ? f.y : (e == 2) ? f.z : f.w);
            }
        }
    } else {
        const __bf16* xg = (const __bf16*)xin;
        constexpr int NSTG = NPB * VSPAN * 8;
        constexpr int ITER = (NSTG + THREADS - 1) / THREADS;
        #pragma unroll
        for (int it = 0; it < ITER; ++it) {
            int idx = it * THREADS + tid;
            if (idx < NSTG) {
                int n_l = idx / (VSPAN * 8);
                int r   = idx - n_l * (VSPAN * 8);
                int v = r >> 3, c8 = (r & 7) * 8;
                int buf = (STRIDE == 2) ? (v & 1) : 0;
                int row = (STRIDE == 2) ? (v >> 1) : v;
                __bf16* dst = sx + ((size_t)(n_l * NBUF + buf) * ROWS + row) * 72 + c8;
                if constexpr (IMODE == 1) {
                    if (v < LIN) {
                        const __bf16* src = xg + (((size_t)(nb + n_l) * LIN + v) * 64 + c8);
                        *(uint4*)dst = *(const uint4*)src;
                    } else {
                        #pragma unroll
                        for (int e = 0; e < 8; ++e) dst[e] = (__bf16)0.f;
                    }
                } else {
                    if (v < LIN) {
                        const __bf16* s0 = xg + (((size_t)(nb + n_l) * 82 + 2 * v) * 64 + c8);
                        #pragma unroll
                        for (int e = 0; e < 8; ++e)
                            dst[e] = (__bf16)(((float)s0[e] + (float)s0[64 + e] +
                                               (float)s0[128 + e]) * (1.f / 3.f));
                    } else {
                        #pragma unroll
                        for (int e = 0; e < 8; ++e) dst[e] = (__bf16)0.f;
                    }
                }
            }
        }
    }

    const int wave = tid >> 6, lane = tid & 63;
    const int n_l  = wave / TPN, tile = wave - n_l * TPN;
    const int m    = lane & 15, quad = lane >> 4;
    const __bf16* sxn = sx + (size_t)n_l * NBUF * ROWS * 72;

    f32x4 acc[3][4];
    #pragma unroll
    for (int mi = 0; mi < 3; ++mi)
        #pragma unroll
        for (int nj = 0; nj < 4; ++nj)
            acc[mi][nj] = (f32x4){0.f, 0.f, 0.f, 0.f};

    for (int kb = 0; kb < K; kb += KCHUNK) {
        if (kb) __syncthreads();
        constexpr int WITER = KCHUNK * 64 * 8 / THREADS;
        #pragma unroll
        for (int it = 0; it < WITER; ++it) {
            int idx = it * THREADS + tid;
            int r = idx >> 3, p = idx & 7;
            *(uint4*)(sw + (size_t)r * 72 + p * 8) =
                *(const uint4*)(wT + (size_t)(kb + (r >> 6)) * 4096 + (r & 63) * 64 + p * 8);
        }
        __syncthreads();

        #pragma unroll
        for (int kp2 = 0; kp2 < KCHUNK; ++kp2) {
            const int kp = kb + kp2;
            const int buf    = (STRIDE == 2) ? (kp & 1) : 0;
            const int rowoff = (STRIDE == 2) ? (kp >> 1) : kp;
            const __bf16* abase = sxn + ((size_t)buf * ROWS + tile * 48 + m + rowoff) * 72;
            const __bf16* bbase = sw + (size_t)(kp2 * 64 + m) * 72;
            #pragma unroll
            for (int s = 0; s < 2; ++s) {
                bf16x8 af[3], bfr[4];
                #pragma unroll
                for (int mi = 0; mi < 3; ++mi)
                    af[mi] = *(const bf16x8*)(abase + mi * (16 * 72) + s * 32 + quad * 8);
                #pragma unroll
                for (int nj = 0; nj < 4; ++nj)
                    bfr[nj] = *(const bf16x8*)(bbase + nj * (16 * 72) + s * 32 + quad * 8);
                #pragma unroll
                for (int mi = 0; mi < 3; ++mi)
                    #pragma unroll
                    for (int nj = 0; nj < 4; ++nj)
                        acc[mi][nj] = __builtin_amdgcn_mfma_f32_16x16x32_bf16(
                            af[mi], bfr[nj], acc[mi][nj], 0, 0, 0);
            }
        }
    }

    #pragma unroll
    for (int nj = 0; nj < 4; ++nj) {
        const int co = nj * 16 + m;
        const float bi = bias[co];
        float scale = 1.f, shift = 0.f;
        if constexpr (DO_BN) {
            float inv = bn_g[co] / sqrtf(bn_v[co] + 1e-5f);
            scale = inv; shift = bn_b[co] - bn_m[co] * inv;
        }
        #pragma unroll
        for (int mi = 0; mi < 3; ++mi) {
            #pragma unroll
            for (int r = 0; r < 4; ++r) {
                int t = tile * 48 + mi * 16 + quad * 4 + r;
                if (t < LOUT) {
                    float v = acc[mi][nj][r] + bi;
                    v = elu_f(v);
                    if constexpr (DO_BN) v = v * scale + shift;
                    y[((size_t)(nb + n_l) * LOUT + t) * 64 + co] = (__bf16)v;
                }
            }
        }
    }
}

// ---------------------------------------------------------------------------
// Attention pooling, one WAVE per (b,c) pair; 4 pairs per 256-thread block.
// W staged once in LDS; all 64 d-partials held in registers (t-outer loop);
// shuffle reductions + in-wave softmax. One barrier total.
// ---------------------------------------------------------------------------
__global__ __launch_bounds__(256) void attn_pool_k(
    const __bf16* __restrict__ h, const float* __restrict__ W,
    const float* __restrict__ ab, const float* __restrict__ u,
    float* __restrict__ out)
{
    __shared__ float sW[35 * 256];       // 35840 B
    __shared__ float sh[4][16 * 35 + 5]; // + pad
    const int tid = threadIdx.x;
    const int pair0 = blockIdx.x * 4;
    for (int i = tid; i < 35 * 256; i += 256) sW[i] = W[i];
    for (int i = tid; i < 4 * 560; i += 256) {
        int q = i / 560, r = i - q * 560;
        int s = r / 35, t = r - s * 35;
        int bc = pair0 + q, b = bc >> 6, c = bc & 63;
        sh[q][s * 35 + t] = (float)h[(((size_t)b * 16 + s) * 35 + t) * 64 + c];
    }
    __syncthreads();

    const int wave = tid >> 6, lane = tid & 63;
    const int bc = pair0 + wave;
    const float* shw = sh[wave];

    float myu[4], myb[4];
    #pragma unroll
    for (int p = 0; p < 4; ++p) { myu[p] = u[lane + 64 * p]; myb[p] = ab[lane + 64 * p]; }

    float dot[16][4];
    #pragma unroll
    for (int s = 0; s < 16; ++s)
        #pragma unroll
        for (int p = 0; p < 4; ++p) dot[s][p] = myb[p];

    for (int t = 0; t < 35; ++t) {
        float w0 = sW[t * 256 + lane];
        float w1 = sW[t * 256 + lane + 64];
        float w2 = sW[t * 256 + lane + 128];
        float w3 = sW[t * 256 + lane + 192];
        #pragma unroll
        for (int s = 0; s < 16; ++s) {
            float hv = shw[s * 35 + t];
            dot[s][0] = fmaf(hv, w0, dot[s][0]);
            dot[s][1] = fmaf(hv, w1, dot[s][1]);
            dot[s][2] = fmaf(hv, w2, dot[s][2]);
            dot[s][3] = fmaf(hv, w3, dot[s][3]);
        }
    }

    float sc[16];
    #pragma unroll
    for (int s = 0; s < 16; ++s) {
        float v = tanhf(dot[s][0]) * myu[0] + tanhf(dot[s][1]) * myu[1]
                + tanhf(dot[s][2]) * myu[2] + tanhf(dot[s][3]) * myu[3];
        #pragma unroll
        for (int off = 1; off < 64; off <<= 1) v += __shfl_xor(v, off, 64);
        sc[s] = v;
    }

    float mx = sc[0];
    #pragma unroll
    for (int s = 1; s < 16; ++s) mx = fmaxf(mx, sc[s]);
    float e[16], sum = 0.f;
    #pragma unroll
    for (int s = 0; s < 16; ++s) { e[s] = expf(sc[s] - mx); sum += e[s]; }
    float inv = 1.f / sum;

    if (lane < 35) {
        float acc = 0.f;
        #pragma unroll
        for (int s = 0; s < 16; ++s) acc = fmaf(shw[s * 35 + lane], e[s] * inv, acc);
        out[(size_t)bc * 35 + lane] = elu_f(acc);
    }
}

// ---------------------------------------------------------------------------
// Fused GIN stack, split-bf16 (hi/lo). 512 threads = 8 waves; each wave owns
// a 32-wide output strip (2 nj fragments).
// ---------------------------------------------------------------------------
#define APLANE (64 * 264)

__device__ __forceinline__ void gin_gemm_dev(
    const __bf16* As,                 // hi plane; lo at As+APLANE
    const __bf16* __restrict__ Wg, int Kpad, int wlo, int Kout,
    const float* __restrict__ bias,
    int mode,                 // 0: relu->A   1: relu, +colsum ->A   2: raw->global
    __bf16* Ad, float* __restrict__ outg)
{
    const int lane = threadIdx.x & 63;
    const int wave = threadIdx.x >> 6;      // 0..7
    const int o0 = wave * 32;
    if (o0 >= ((Kout + 63) & ~63)) return;
    const int m = lane & 15, quad = lane >> 4;

    f32x4 acc[4][2];
    #pragma unroll
    for (int mi = 0; mi < 4; ++mi)
        #pragma unroll
        for (int nj = 0; nj < 2; ++nj)
            acc[mi][nj] = (f32x4){0.f, 0.f, 0.f, 0.f};

    for (int k0 = 0; k0 < Kpad; k0 += 32) {
        bf16x8 ah[4], al[4], bh[2], bl[2];
        #pragma unroll
        for (int mi = 0; mi < 4; ++mi) {
            const __bf16* ap = As + (size_t)(mi * 16 + m) * 264 + k0 + quad * 8;
            ah[mi] = *(const bf16x8*)ap;
            al[mi] = *(const bf16x8*)(ap + APLANE);
        }
        #pragma unroll
        for (int nj = 0; nj < 2; ++nj) {
            const __bf16* wp = Wg + (size_t)(o0 + nj * 16 + m) * Kpad + k0 + quad * 8;
            bh[nj] = *(const bf16x8*)wp;
            bl[nj] = *(const bf16x8*)(wp + wlo);
        }
        #pragma unroll
        for (int mi = 0; mi < 4; ++mi)
            #pragma unroll
            for (int nj = 0; nj < 2; ++nj) {
                acc[mi][nj] = __builtin_amdgcn_mfma_f32_16x16x32_bf16(
                    al[mi], bh[nj], acc[mi][nj], 0, 0, 0);
                acc[mi][nj] = __builtin_amdgcn_mfma_f32_16x16x32_bf16(
                    ah[mi], bl[nj], acc[mi][nj], 0, 0, 0);
                acc[mi][nj] = __builtin_amdgcn_mfma_f32_16x16x32_bf16(
                    ah[mi], bh[nj], acc[mi][nj], 0, 0, 0);
            }
    }

    #pragma unroll
    for (int nj = 0; nj < 2; ++nj) {
        const int o = o0 + nj * 16 + m;
        const bool ovalid = (o < Kout);
        const float bi = ovalid ? bias[o] : 0.f;
        float v[4][4];
        #pragma unroll
        for (int mi = 0; mi < 4; ++mi)
            #pragma unroll
            for (int r = 0; r < 4; ++r)
                v[mi][r] = acc[mi][nj][r] + bi;
        if (mode == 2) {
            if (ovalid) {
                #pragma unroll
                for (int mi = 0; mi < 4; ++mi)
                    #pragma unroll
                    for (int r = 0; r < 4; ++r)
                        outg[(size_t)(mi * 16 + quad * 4 + r) * Kout + o] = v[mi][r];
            }
        } else {
            float s = 0.f;
            #pragma unroll
            for (int mi = 0; mi < 4; ++mi)
                #pragma unroll
                for (int r = 0; r < 4; ++r) {
                    float rv = ovalid ? fmaxf(v[mi][r], 0.f) : 0.f;
                    v[mi][r] = rv;
                    s += rv;
                }
            if (mode == 1) {
                s += __shfl_xor(s, 16, 64);
                s += __shfl_xor(s, 32, 64);
            } else {
                s = 0.f;
            }
            #pragma unroll
            for (int mi = 0; mi < 4; ++mi)
                #pragma unroll
                for (int r = 0; r < 4; ++r) {
                    float a = v[mi][r] + s;
                    __bf16 hi = (__bf16)a;
                    size_t pos = (size_t)(mi * 16 + quad * 4 + r) * 264 + o;
                    Ad[pos] = hi;
                    Ad[APLANE + pos] = (__bf16)(a - (float)hi);
                }
        }
    }
}

__global__ __launch_bounds__(512) void gin_fused(
    const float* __restrict__ ha,
    const __bf16* __restrict__ gW0a, const __bf16* __restrict__ gW0b,
    const __bf16* __restrict__ gW1a, const __bf16* __restrict__ gW1b,
    const __bf16* __restrict__ gW2a, const __bf16* __restrict__ gW2b,
    const float* __restrict__ b0a, const float* __restrict__ b0b,
    const float* __restrict__ b1a, const float* __restrict__ b1b,
    const float* __restrict__ b2a, const float* __restrict__ b2b,
    float* __restrict__ H3)
{
    const int b = blockIdx.x, tid = threadIdx.x;
    __shared__ __align__(16) __bf16 sA[2][2 * APLANE];
    __shared__ float sS[64];
    const float* hab = ha + (size_t)b * 2240;

    if (tid < 64) {
        float s = 0.f;
        if (tid < 35)
            for (int n = 0; n < 64; ++n) s += hab[n * 35 + tid];
        sS[tid] = s;
    }
    __syncthreads();
    for (int idx = tid; idx < 64 * 64; idx += 512) {
        int n = idx >> 6, k = idx & 63;
        float a = (k < 35) ? hab[n * 35 + k] + sS[k] : 0.f;
        __bf16 hi = (__bf16)a;
        sA[0][n * 264 + k] = hi;
        sA[0][APLANE + n * 264 + k] = (__bf16)(a - (float)hi);
    }
    __syncthreads();

    gin_gemm_dev(sA[0], gW0a, 64,  16384, 256, b0a, 0, sA[1], nullptr); __syncthreads();
    gin_gemm_dev(sA[1], gW0b, 256, 65536, 256, b0b, 1, sA[0], nullptr); __syncthreads();
    gin_gemm_dev(sA[0], gW1a, 256, 65536, 256, b1a, 0, sA[1], nullptr); __syncthreads();
    gin_gemm_dev(sA[1], gW1b, 256, 65536, 256, b1b, 1, sA[0], nullptr); __syncthreads();
    gin_gemm_dev(sA[0], gW2a, 256, 16384, 35,  b2a, 0, sA[1], nullptr); __syncthreads();
    gin_gemm_dev(sA[1], gW2b, 64,  4096,  35,  b2b, 2, nullptr, H3 + (size_t)b * 2240);
}

// ---------------------------------------------------------------------------
// Classifier layer 1, fp32, K-split: grid (b=32, kc=16).
// ---------------------------------------------------------------------------
__global__ __launch_bounds__(256) void cls1_part_k(
    const float* __restrict__ H3, const float* __restrict__ w1,
    float* __restrict__ s1p)
{
    const int b  = blockIdx.x;
    const int kc = blockIdx.y;
    const int k0 = kc * 140;
    __shared__ float sH[140];
    const int tid = threadIdx.x;
    if (tid < 140) sH[tid] = H3[(size_t)b * 2240 + k0 + tid];
    __syncthreads();
    const int o = (tid >> 6) * 64 + (tid & 63);
    float a0 = 0.f, a1 = 0.f, a2 = 0.f, a3 = 0.f;
    const float* wr = w1 + (size_t)k0 * 256 + o;
    #pragma unroll
    for (int k = 0; k < 140; k += 4) {
        a0 = fmaf(sH[k],     wr[(size_t)k * 256],       a0);
        a1 = fmaf(sH[k + 1], wr[(size_t)(k + 1) * 256], a1);
        a2 = fmaf(sH[k + 2], wr[(size_t)(k + 2) * 256], a2);
        a3 = fmaf(sH[k + 3], wr[(size_t)(k + 3) * 256], a3);
    }
    s1p[((size_t)kc * 32 + b) * 256 + o] = a0 + a1 + a2 + a3;
}

// ---------------------------------------------------------------------------
// Classifier: reduce K-split partials (+bias, ELU), then layers 2-4 (fp32).
// ---------------------------------------------------------------------------
__global__ __launch_bounds__(256) void cls234_k(
    const float* __restrict__ s1p, const float* __restrict__ b1,
    const float* __restrict__ w2, const float* __restrict__ b2,
    const float* __restrict__ w3, const float* __restrict__ b3,
    const float* __restrict__ w4, const float* __restrict__ b4,
    float* __restrict__ out)
{
    const int b = blockIdx.x, tid = threadIdx.x;
    __shared__ float s1[256];
    __shared__ float part[4][64];
    __shared__ float s2[64];
    __shared__ float s3[16];
    {
        float acc = b1[tid];
        #pragma unroll
        for (int kc = 0; kc < 16; ++kc)
            acc += s1p[((size_t)kc * 32 + b) * 256 + tid];
        s1[tid] = elu_f(acc);
    }
    __syncthreads();
    {
        int kg = tid >> 6, o = tid & 63;
        float acc = 0.f;
        for (int k = kg * 64; k < kg * 64 + 64; ++k)
            acc = fmaf(s1[k], w2[k * 64 + o], acc);
        part[kg][o] = acc;
    }
    __syncthreads();
    if (tid < 64) {
        float acc = part[0][tid] + part[1][tid] + part[2][tid] + part[3][tid] + b2[tid];
        s2[tid] = elu_f(acc);
    }
    __syncthreads();
    if (tid < 16) {
        float acc = b3[tid];
        for (int k = 0; k < 64; ++k) acc = fmaf(s2[k], w3[k * 16 + tid], acc);
        s3[tid] = elu_f(acc);
    }
    __syncthreads();
    if (tid < 2) {
        float acc = b4[tid];
        for (int k = 0; k < 16; ++k) acc = fmaf(s3[k], w4[k * 2 + tid], acc);
        out[b * 2 + tid] = acc;
    }
}

// ---------------------------------------------------------------------------
extern "C" void kernel_launch(void* const* d_in, const int* in_sizes, int n_in,
                              void* d_out, int out_size, void* d_ws, size_t ws_size,
                              hipStream_t stream)
{
    const float* x     = (const float*)d_in[0];
    const float* w1    = (const float*)d_in[1];
    const float* b1    = (const float*)d_in[2];
    const float* bn1_g = (const float*)d_in[3];
    const float* bn1_b = (const float*)d_in[4];
    const float* bn1_m = (const float*)d_in[5];
    const float* bn1_v = (const float*)d_in[6];
    const float* w2    = (const float*)d_in[7];
    const float* b2    = (const float*)d_in[8];
    const float* bn2_g = (const float*)d_in[9];
    const float* bn2_b = (const float*)d_in[10];
    const float* bn2_m = (const float*)d_in[11];
    const float* bn2_v = (const float*)d_in[12];
    const float* w3    = (const float*)d_in[13];
    const float* b3    = (const float*)d_in[14];
    const float* w4    = (const float*)d_in[15];
    const float* b4    = (const float*)d_in[16];
    const float* attn_w = (const float*)d_in[17];
    const float* attn_b = (const float*)d_in[18];
    const float* attn_u = (const float*)d_in[19];
    const float* g0_w1 = (const float*)d_in[20];
    const float* g0_b1 = (const float*)d_in[21];
    const float* g0_w2 = (const float*)d_in[22];
    const float* g0_b2 = (const float*)d_in[23];
    const float* g1_w1 = (const float*)d_in[24];
    const float* g1_b1 = (const float*)d_in[25];
    const float* g1_w2 = (const float*)d_in[26];
    const float* g1_b2 = (const float*)d_in[27];
    const float* g2_w1 = (const float*)d_in[28];
    const float* g2_b1 = (const float*)d_in[29];
    const float* g2_w2 = (const float*)d_in[30];
    const float* g2_b2 = (const float*)d_in[31];
    const float* c_w1  = (const float*)d_in[32];
    const float* c_b1  = (const float*)d_in[33];
    const float* c_w2  = (const float*)d_in[34];
    const float* c_b2  = (const float*)d_in[35];
    const float* c_w3  = (const float*)d_in[36];
    const float* c_b3  = (const float*)d_in[37];
    const float* c_w4  = (const float*)d_in[38];
    const float* c_b4  = (const float*)d_in[39];
    float* out = (float*)d_out;

    char* ws = (char*)d_ws;
    __bf16* wT1  = (__bf16*)(ws + 0);
    __bf16* wT2  = (__bf16*)(ws + 163840);
    __bf16* wT3  = (__bf16*)(ws + 327680);
    __bf16* wT4  = (__bf16*)(ws + 376832);
    __bf16* h1   = (__bf16*)(ws + 425984);     // [512][192][64]
    __bf16* h2   = (__bf16*)(ws + 13008896);   // [512][87][64]
    __bf16* h3   = (__bf16*)(ws + 18710528);   // [512][82][64]
    __bf16* h4   = (__bf16*)(ws + 24084480);   // [512][35][64]
    float*  ha   = (float*)(ws + 26378240);    // [32][64][35]
    __bf16* gW0a = (__bf16*)(ws + 26664960);   // hi+lo [256][64]   65536 B
    __bf16* gW0b = (__bf16*)(ws + 26730496);   // hi+lo [256][256] 262144 B
    __bf16* gW1a = (__bf16*)(ws + 26992640);
    __bf16* gW1b = (__bf16*)(ws + 27254784);
    __bf16* gW2a = (__bf16*)(ws + 27516928);   // hi+lo [64][256]   65536 B
    __bf16* gW2b = (__bf16*)(ws + 27582464);   // hi+lo [64][64]    16384 B
    float*  H3   = (float*)(ws + 27598848);    // [32][2240]
    float*  s1p  = (float*)(ws + 27885568);    // [16][32][256] = 524288 B

    prep_weights<<<dim3(832), dim3(256), 0, stream>>>(w1, w2, w3, w4, wT1, wT2, wT3, wT4);
    prep_tr<<<dim3(57), dim3(256), 0, stream>>>(g0_w1, g0_w2, g1_w1, g1_w2, g2_w1, g2_w2,
                                                gW0a, gW0b, gW1a, gW1b, gW2a, gW2b);

    // CNN stack: round-8 proven config (KCHUNK=2 LDS weight staging)
    conv_mfma<20, 2, 1, true, 0, 1, 4, 400, 192, 2><<<dim3(512), dim3(256), 0, stream>>>(
        x, wT1, b1, bn1_g, bn1_b, bn1_m, bn1_v, h1);
    conv_mfma<20, 2, 0, true, 1, 1, 2, 192, 87, 2><<<dim3(512), dim3(128), 0, stream>>>(
        h1, wT2, b2, bn2_g, bn2_b, bn2_m, bn2_v, h2);
    conv_mfma<6, 1, 0, false, 1, 1, 2, 87, 82, 2><<<dim3(512), dim3(128), 0, stream>>>(
        h2, wT3, b3, nullptr, nullptr, nullptr, nullptr, h3);
    conv_mfma<6, 1, 0, false, 2, 2, 1, 40, 35, 2><<<dim3(256), dim3(128), 0, stream>>>(
        h3, wT4, b4, nullptr, nullptr, nullptr, nullptr, h4);

    attn_pool_k<<<dim3(512), dim3(256), 0, stream>>>(h4, attn_w, attn_b, attn_u, ha);

    gin_fused<<<dim3(32), dim3(512), 0, stream>>>(
        ha, gW0a, gW0b, gW1a, gW1b, gW2a, gW2b,
        g0_b1, g0_b2, g1_b1, g1_b2, g2_b1, g2_b2, H3);

    cls1_part_k<<<dim3(32, 16), dim3(256), 0, stream>>>(H3, c_w1, s1p);
    cls234_k<<<dim3(32), dim3(256), 0, stream>>>(s1p, c_b1, c_w2, c_b2, c_w3, c_b3,
                                                 c_w4, c_b4, out);
}

// Round 12
// 303.075 us; speedup vs baseline: 1.2498x; 1.0646x over previous
//
#include <hip/hip_runtime.h>
#include <math.h>

typedef __attribute__((ext_vector_type(8))) __bf16 bf16x8;
typedef __attribute__((ext_vector_type(4))) float f32x4;

__device__ __forceinline__ float elu_f(float v) {
    return v > 0.f ? v : (expf(v) - 1.f);
}

// ---------------------------------------------------------------------------
// Conv weight reorder: w[co][ci][K] fp32 -> wT[k][co][ci] bf16 (all 4 convs).
// ---------------------------------------------------------------------------
__global__ __launch_bounds__(256) void prep_weights(
    const float* __restrict__ w1, const float* __restrict__ w2,
    const float* __restrict__ w3, const float* __restrict__ w4,
    __bf16* __restrict__ t1, __bf16* __restrict__ t2,
    __bf16* __restrict__ t3, __bf16* __restrict__ t4)
{
    int idx = blockIdx.x * 256 + threadIdx.x;
    if (idx < 81920) {
        int k = idx / 4096, r = idx - k * 4096, co = r >> 6, ci = r & 63;
        t1[idx] = (__bf16)w1[(co * 64 + ci) * 20 + k];
    } else if (idx < 163840) {
        int j = idx - 81920;
        int k = j / 4096, r = j - k * 4096, co = r >> 6, ci = r & 63;
        t2[j] = (__bf16)w2[(co * 64 + ci) * 20 + k];
    } else if (idx < 188416) {
        int j = idx - 163840;
        int k = j / 4096, r = j - k * 4096, co = r >> 6, ci = r & 63;
        t3[j] = (__bf16)w3[(co * 64 + ci) * 6 + k];
    } else if (idx < 212992) {
        int j = idx - 188416;
        int k = j / 4096, r = j - k * 4096, co = r >> 6, ci = r & 63;
        t4[j] = (__bf16)w4[(co * 64 + ci) * 6 + k];
    }
}

// ---------------------------------------------------------------------------
// Tiled transpose+convert with hi/lo split for GIN weights. 57 blocks.
// ---------------------------------------------------------------------------
__global__ __launch_bounds__(256) void prep_tr(
    const float* __restrict__ g0w1, const float* __restrict__ g0w2,
    const float* __restrict__ g1w1, const float* __restrict__ g1w2,
    const float* __restrict__ g2w1, const float* __restrict__ g2w2,
    __bf16* __restrict__ d0, __bf16* __restrict__ d1, __bf16* __restrict__ d2,
    __bf16* __restrict__ d3, __bf16* __restrict__ d4, __bf16* __restrict__ d5)
{
    int bid = blockIdx.x;
    const float* src; __bf16* dst; int K, O, Kpad, Opad, tile;
    if (bid < 4)       { src = g0w1; dst = d0; K = 35;   O = 256; Kpad = 64;   Opad = 256; tile = bid; }
    else if (bid < 20) { src = g0w2; dst = d1; K = 256;  O = 256; Kpad = 256;  Opad = 256; tile = bid - 4; }
    else if (bid < 36) { src = g1w1; dst = d2; K = 256;  O = 256; Kpad = 256;  Opad = 256; tile = bid - 20; }
    else if (bid < 52) { src = g1w2; dst = d3; K = 256;  O = 256; Kpad = 256;  Opad = 256; tile = bid - 36; }
    else if (bid < 56) { src = g2w1; dst = d4; K = 256;  O = 35;  Kpad = 256;  Opad = 64;  tile = bid - 52; }
    else               { src = g2w2; dst = d5; K = 35;   O = 35;  Kpad = 64;   Opad = 64;  tile = 0; }
    int ktiles = Kpad >> 6;
    int ot = tile / ktiles, kt = tile - ot * ktiles;
    int k0 = kt * 64, o0 = ot * 64;
    size_t LOFF = (size_t)Opad * Kpad;
    __shared__ float tl[64][68];
    int c = threadIdx.x & 63, rr = threadIdx.x >> 6;
    #pragma unroll
    for (int it = 0; it < 16; ++it) {
        int r = rr + it * 4;
        int kk = k0 + r, oo = o0 + c;
        tl[r][c] = (kk < K && oo < O) ? src[(size_t)kk * O + oo] : 0.f;
    }
    __syncthreads();
    #pragma unroll
    for (int it = 0; it < 16; ++it) {
        int r = rr + it * 4;
        float v = tl[c][r];
        __bf16 hi = (__bf16)v;
        float lo = v - (float)hi;
        size_t pos = (size_t)(o0 + r) * Kpad + k0 + c;
        dst[pos] = hi;
        dst[LOFF + pos] = (__bf16)lo;
    }
}

// ---------------------------------------------------------------------------
// MFMA conv1 (round-8 proven config). fp32 [ci][400] in -> [n][192][64] bf16.
// ---------------------------------------------------------------------------
template<int K, int STRIDE, int PAD, bool DO_BN, int IMODE,
         int NPB, int TPN, int LIN, int LOUT, int KCHUNK>
__global__ __launch_bounds__(NPB * TPN * 64, 2) void conv_mfma(
    const void* __restrict__ xin, const __bf16* __restrict__ wT,
    const float* __restrict__ bias,
    const float* __restrict__ bn_g, const float* __restrict__ bn_b,
    const float* __restrict__ bn_m, const float* __restrict__ bn_v,
    __bf16* __restrict__ y)
{
    constexpr int THREADS = NPB * TPN * 64;
    constexpr int TBLK  = TPN * 48;
    constexpr int VSPAN = STRIDE * (TBLK - 1) + K;
    constexpr int NBUF  = (STRIDE == 2) ? 2 : 1;
    constexpr int ROWS  = (VSPAN + NBUF - 1) / NBUF;
    __shared__ __align__(16) __bf16 sx[NPB * NBUF * ROWS * 72];
    __shared__ __align__(16) __bf16 sw[KCHUNK * 64 * 72];

    const int tid = threadIdx.x;
    const int nb  = blockIdx.x * NPB;

    if constexpr (IMODE == 0) {
        const float* xg = (const float*)xin + (size_t)nb * 64 * LIN;
        constexpr int NZROWS = PAD + (VSPAN - LIN - PAD);
        if (tid < NZROWS * 64) {
            int zr = tid >> 6;
            int v = (zr < PAD) ? zr : (LIN + PAD + zr - PAD);
            sx[((v & (NBUF - 1)) * ROWS + (v >> (NBUF - 1))) * 72 + (tid & 63)] = (__bf16)0.f;
        }
        constexpr int J4 = LIN / 4;
        constexpr int NCH = 64 * J4;
        constexpr int ITER = NCH / THREADS;
        #pragma unroll
        for (int it = 0; it < ITER; ++it) {
            int idx = it * THREADS + tid;
            int ci = idx / J4, j = idx - ci * J4;
            float4 f = *(const float4*)(xg + (size_t)ci * LIN + 4 * j);
            #pragma unroll
            for (int e = 0; e < 4; ++e) {
                int v = 4 * j + e + PAD;
                sx[((v & (NBUF - 1)) * ROWS + (v >> (NBUF - 1))) * 72 + ci] =
                    (__bf16)((e == 0) ? f.x : (e == 1) ? f.y : (e == 2) ? f.z : f.w);
            }
        }
    }

    const int wave = tid >> 6, lane = tid & 63;
    const int n_l  = wave / TPN, tile = wave - n_l * TPN;
    const int m    = lane & 15, quad = lane >> 4;
    const __bf16* sxn = sx + (size_t)n_l * NBUF * ROWS * 72;

    f32x4 acc[3][4];
    #pragma unroll
    for (int mi = 0; mi < 3; ++mi)
        #pragma unroll
        for (int nj = 0; nj < 4; ++nj)
            acc[mi][nj] = (f32x4){0.f, 0.f, 0.f, 0.f};

    for (int kb = 0; kb < K; kb += KCHUNK) {
        if (kb) __syncthreads();
        constexpr int WITER = KCHUNK * 64 * 8 / THREADS;
        #pragma unroll
        for (int it = 0; it < WITER; ++it) {
            int idx = it * THREADS + tid;
            int r = idx >> 3, p = idx & 7;
            *(uint4*)(sw + (size_t)r * 72 + p * 8) =
                *(const uint4*)(wT + (size_t)(kb + (r >> 6)) * 4096 + (r & 63) * 64 + p * 8);
        }
        __syncthreads();

        #pragma unroll
        for (int kp2 = 0; kp2 < KCHUNK; ++kp2) {
            const int kp = kb + kp2;
            const int buf    = (STRIDE == 2) ? (kp & 1) : 0;
            const int rowoff = (STRIDE == 2) ? (kp >> 1) : kp;
            const __bf16* abase = sxn + ((size_t)buf * ROWS + tile * 48 + m + rowoff) * 72;
            const __bf16* bbase = sw + (size_t)(kp2 * 64 + m) * 72;
            #pragma unroll
            for (int s = 0; s < 2; ++s) {
                bf16x8 af[3], bfr[4];
                #pragma unroll
                for (int mi = 0; mi < 3; ++mi)
                    af[mi] = *(const bf16x8*)(abase + mi * (16 * 72) + s * 32 + quad * 8);
                #pragma unroll
                for (int nj = 0; nj < 4; ++nj)
                    bfr[nj] = *(const bf16x8*)(bbase + nj * (16 * 72) + s * 32 + quad * 8);
                #pragma unroll
                for (int mi = 0; mi < 3; ++mi)
                    #pragma unroll
                    for (int nj = 0; nj < 4; ++nj)
                        acc[mi][nj] = __builtin_amdgcn_mfma_f32_16x16x32_bf16(
                            af[mi], bfr[nj], acc[mi][nj], 0, 0, 0);
            }
        }
    }

    #pragma unroll
    for (int nj = 0; nj < 4; ++nj) {
        const int co = nj * 16 + m;
        const float bi = bias[co];
        float scale = 1.f, shift = 0.f;
        if constexpr (DO_BN) {
            float inv = bn_g[co] / sqrtf(bn_v[co] + 1e-5f);
            scale = inv; shift = bn_b[co] - bn_m[co] * inv;
        }
        #pragma unroll
        for (int mi = 0; mi < 3; ++mi) {
            #pragma unroll
            for (int r = 0; r < 4; ++r) {
                int t = tile * 48 + mi * 16 + quad * 4 + r;
                if (t < LOUT) {
                    float v = acc[mi][nj][r] + bi;
                    v = elu_f(v);
                    if constexpr (DO_BN) v = v * scale + shift;
                    y[((size_t)(nb + n_l) * LOUT + t) * 64 + co] = (__bf16)v;
                }
            }
        }
    }
}

// ---------------------------------------------------------------------------
// Fused conv2 -> conv3 -> avgpool3/s2 -> conv4, one block per sample.
// 128 threads (2 waves). All intermediates in LDS; same per-value math as
// the separate kernels (bitwise-identical h4). Out-of-range A-rows clamped
// (those outputs are masked in the epilogues).
// ---------------------------------------------------------------------------
__global__ __launch_bounds__(128, 2) void conv234_fused(
    const __bf16* __restrict__ h1,
    const __bf16* __restrict__ wT2, const float* __restrict__ b2,
    const float* __restrict__ bn2g, const float* __restrict__ bn2b,
    const float* __restrict__ bn2m, const float* __restrict__ bn2v,
    const __bf16* __restrict__ wT3, const float* __restrict__ b3,
    const __bf16* __restrict__ wT4, const float* __restrict__ b4,
    __bf16* __restrict__ h4)
{
    __shared__ __align__(16) __bf16 bufA[2 * 96 * 72];   // h1 stage / c3 out
    __shared__ __align__(16) __bf16 bufB[87 * 72];       // c2 out / pooled
    __shared__ __align__(16) __bf16 sw[2 * 64 * 72];

    const int tid = threadIdx.x;
    const int n = blockIdx.x;
    const int wave = tid >> 6, lane = tid & 63;
    const int m = lane & 15, quad = lane >> 4;

    // ---- stage h1[n]: [192][64] -> parity-split [2][96][72] ----
    {
        const __bf16* src = h1 + (size_t)n * 192 * 64;
        #pragma unroll
        for (int it = 0; it < 12; ++it) {
            int idx = it * 128 + tid;
            int v = idx >> 3, c8 = (idx & 7) * 8;
            *(uint4*)(bufA + ((size_t)(v & 1) * 96 + (v >> 1)) * 72 + c8) =
                *(const uint4*)(src + (size_t)v * 64 + c8);
        }
    }
    __syncthreads();

    f32x4 acc[3][4];
    // ================= conv2: K=20, stride 2, BN+ELU =================
    #pragma unroll
    for (int mi = 0; mi < 3; ++mi)
        #pragma unroll
        for (int nj = 0; nj < 4; ++nj)
            acc[mi][nj] = (f32x4){0.f, 0.f, 0.f, 0.f};

    for (int kb = 0; kb < 20; kb += 2) {
        if (kb) __syncthreads();
        #pragma unroll
        for (int it = 0; it < 8; ++it) {
            int idx = it * 128 + tid;
            int r = idx >> 3, p = idx & 7;
            *(uint4*)(sw + (size_t)r * 72 + p * 8) =
                *(const uint4*)(wT2 + (size_t)(kb + (r >> 6)) * 4096 + (r & 63) * 64 + p * 8);
        }
        __syncthreads();
        #pragma unroll
        for (int kp2 = 0; kp2 < 2; ++kp2) {
            const int kp = kb + kp2;
            const int buf = kp & 1, rowoff = kp >> 1;
            const int r0 = wave * 48 + m + rowoff;
            const __bf16* bbase = sw + (size_t)(kp2 * 64 + m) * 72;
            #pragma unroll
            for (int s = 0; s < 2; ++s) {
                bf16x8 af[3], bfr[4];
                #pragma unroll
                for (int mi = 0; mi < 3; ++mi) {
                    int rr = r0 + mi * 16; if (rr > 95) rr = 95;
                    af[mi] = *(const bf16x8*)(bufA + ((size_t)buf * 96 + rr) * 72 + s * 32 + quad * 8);
                }
                #pragma unroll
                for (int nj = 0; nj < 4; ++nj)
                    bfr[nj] = *(const bf16x8*)(bbase + nj * (16 * 72) + s * 32 + quad * 8);
                #pragma unroll
                for (int mi = 0; mi < 3; ++mi)
                    #pragma unroll
                    for (int nj = 0; nj < 4; ++nj)
                        acc[mi][nj] = __builtin_amdgcn_mfma_f32_16x16x32_bf16(
                            af[mi], bfr[nj], acc[mi][nj], 0, 0, 0);
            }
        }
    }
    __syncthreads();   // bufA reads done; bufB writes next
    #pragma unroll
    for (int nj = 0; nj < 4; ++nj) {
        const int co = nj * 16 + m;
        const float bi = b2[co];
        float inv = bn2g[co] / sqrtf(bn2v[co] + 1e-5f);
        float shift = bn2b[co] - bn2m[co] * inv;
        #pragma unroll
        for (int mi = 0; mi < 3; ++mi)
            #pragma unroll
            for (int r = 0; r < 4; ++r) {
                int t = wave * 48 + mi * 16 + quad * 4 + r;
                if (t < 87) {
                    float v = elu_f(acc[mi][nj][r] + bi) * inv + shift;
                    bufB[t * 72 + co] = (__bf16)v;
                }
            }
    }
    __syncthreads();

    // ================= conv3: K=6, stride 1, ELU =================
    #pragma unroll
    for (int mi = 0; mi < 3; ++mi)
        #pragma unroll
        for (int nj = 0; nj < 4; ++nj)
            acc[mi][nj] = (f32x4){0.f, 0.f, 0.f, 0.f};

    for (int kb = 0; kb < 6; kb += 2) {
        if (kb) __syncthreads();
        #pragma unroll
        for (int it = 0; it < 8; ++it) {
            int idx = it * 128 + tid;
            int r = idx >> 3, p = idx & 7;
            *(uint4*)(sw + (size_t)r * 72 + p * 8) =
                *(const uint4*)(wT3 + (size_t)(kb + (r >> 6)) * 4096 + (r & 63) * 64 + p * 8);
        }
        __syncthreads();
        #pragma unroll
        for (int kp2 = 0; kp2 < 2; ++kp2) {
            const int kp = kb + kp2;
            const int r0 = wave * 48 + m + kp;
            const __bf16* bbase = sw + (size_t)(kp2 * 64 + m) * 72;
            #pragma unroll
            for (int s = 0; s < 2; ++s) {
                bf16x8 af[3], bfr[4];
                #pragma unroll
                for (int mi = 0; mi < 3; ++mi) {
                    int rr = r0 + mi * 16; if (rr > 86) rr = 86;
                    af[mi] = *(const bf16x8*)(bufB + (size_t)rr * 72 + s * 32 + quad * 8);
                }
                #pragma unroll
                for (int nj = 0; nj < 4; ++nj)
                    bfr[nj] = *(const bf16x8*)(bbase + nj * (16 * 72) + s * 32 + quad * 8);
                #pragma unroll
                for (int mi = 0; mi < 3; ++mi)
                    #pragma unroll
                    for (int nj = 0; nj < 4; ++nj)
                        acc[mi][nj] = __builtin_amdgcn_mfma_f32_16x16x32_bf16(
                            af[mi], bfr[nj], acc[mi][nj], 0, 0, 0);
            }
        }
    }
    __syncthreads();   // bufB reads done; bufA writes next
    #pragma unroll
    for (int nj = 0; nj < 4; ++nj) {
        const int co = nj * 16 + m;
        const float bi = b3[co];
        #pragma unroll
        for (int mi = 0; mi < 3; ++mi)
            #pragma unroll
            for (int r = 0; r < 4; ++r) {
                int t = wave * 48 + mi * 16 + quad * 4 + r;
                if (t < 82)
                    bufA[t * 72 + co] = (__bf16)elu_f(acc[mi][nj][r] + bi);
            }
    }
    __syncthreads();

    // ================= avgpool3/s2: 82 -> 40, into bufB =================
    #pragma unroll
    for (int it = 0; it < 20; ++it) {
        int idx = it * 128 + tid;
        int t = idx >> 6, co = idx & 63;
        float v = ((float)bufA[(2 * t) * 72 + co] + (float)bufA[(2 * t + 1) * 72 + co] +
                   (float)bufA[(2 * t + 2) * 72 + co]) * (1.f / 3.f);
        bufB[t * 72 + co] = (__bf16)v;
    }
    __syncthreads();

    // ================= conv4: K=6, stride 1, ELU; wave = co-half =========
    f32x4 acc4[3][2];
    #pragma unroll
    for (int mi = 0; mi < 3; ++mi)
        #pragma unroll
        for (int nj = 0; nj < 2; ++nj)
            acc4[mi][nj] = (f32x4){0.f, 0.f, 0.f, 0.f};
    const int coh = wave * 32;

    for (int kb = 0; kb < 6; kb += 2) {
        if (kb) __syncthreads();
        #pragma unroll
        for (int it = 0; it < 8; ++it) {
            int idx = it * 128 + tid;
            int r = idx >> 3, p = idx & 7;
            *(uint4*)(sw + (size_t)r * 72 + p * 8) =
                *(const uint4*)(wT4 + (size_t)(kb + (r >> 6)) * 4096 + (r & 63) * 64 + p * 8);
        }
        __syncthreads();
        #pragma unroll
        for (int kp2 = 0; kp2 < 2; ++kp2) {
            const int kp = kb + kp2;
            const int r0 = m + kp;
            const __bf16* bbase = sw + (size_t)(kp2 * 64 + coh + m) * 72;
            #pragma unroll
            for (int s = 0; s < 2; ++s) {
                bf16x8 af[3], bfr[2];
                #pragma unroll
                for (int mi = 0; mi < 3; ++mi) {
                    int rr = r0 + mi * 16; if (rr > 39) rr = 39;
                    af[mi] = *(const bf16x8*)(bufB + (size_t)rr * 72 + s * 32 + quad * 8);
                }
                #pragma unroll
                for (int nj = 0; nj < 2; ++nj)
                    bfr[nj] = *(const bf16x8*)(bbase + nj * (16 * 72) + s * 32 + quad * 8);
                #pragma unroll
                for (int mi = 0; mi < 3; ++mi)
                    #pragma unroll
                    for (int nj = 0; nj < 2; ++nj)
                        acc4[mi][nj] = __builtin_amdgcn_mfma_f32_16x16x32_bf16(
                            af[mi], bfr[nj], acc4[mi][nj], 0, 0, 0);
            }
        }
    }
    #pragma unroll
    for (int nj = 0; nj < 2; ++nj) {
        const int co = coh + nj * 16 + m;
        const float bi = b4[co];
        #pragma unroll
        for (int mi = 0; mi < 3; ++mi)
            #pragma unroll
            for (int r = 0; r < 4; ++r) {
                int t = mi * 16 + quad * 4 + r;
                if (t < 35)
                    h4[((size_t)n * 35 + t) * 64 + co] = (__bf16)elu_f(acc4[mi][nj][r] + bi);
            }
    }
}

// ---------------------------------------------------------------------------
// Attention pooling, one WAVE per (b,c) pair; 4 pairs per 256-thread block.
// ---------------------------------------------------------------------------
__global__ __launch_bounds__(256) void attn_pool_k(
    const __bf16* __restrict__ h, const float* __restrict__ W,
    const float* __restrict__ ab, const float* __restrict__ u,
    float* __restrict__ out)
{
    __shared__ float sW[35 * 256];
    __shared__ float sh[4][16 * 35 + 5];
    const int tid = threadIdx.x;
    const int pair0 = blockIdx.x * 4;
    for (int i = tid; i < 35 * 256; i += 256) sW[i] = W[i];
    for (int i = tid; i < 4 * 560; i += 256) {
        int q = i / 560, r = i - q * 560;
        int s = r / 35, t = r - s * 35;
        int bc = pair0 + q, b = bc >> 6, c = bc & 63;
        sh[q][s * 35 + t] = (float)h[(((size_t)b * 16 + s) * 35 + t) * 64 + c];
    }
    __syncthreads();

    const int wave = tid >> 6, lane = tid & 63;
    const int bc = pair0 + wave;
    const float* shw = sh[wave];

    float myu[4], myb[4];
    #pragma unroll
    for (int p = 0; p < 4; ++p) { myu[p] = u[lane + 64 * p]; myb[p] = ab[lane + 64 * p]; }

    float dot[16][4];
    #pragma unroll
    for (int s = 0; s < 16; ++s)
        #pragma unroll
        for (int p = 0; p < 4; ++p) dot[s][p] = myb[p];

    for (int t = 0; t < 35; ++t) {
        float w0 = sW[t * 256 + lane];
        float w1 = sW[t * 256 + lane + 64];
        float w2 = sW[t * 256 + lane + 128];
        float w3 = sW[t * 256 + lane + 192];
        #pragma unroll
        for (int s = 0; s < 16; ++s) {
            float hv = shw[s * 35 + t];
            dot[s][0] = fmaf(hv, w0, dot[s][0]);
            dot[s][1] = fmaf(hv, w1, dot[s][1]);
            dot[s][2] = fmaf(hv, w2, dot[s][2]);
            dot[s][3] = fmaf(hv, w3, dot[s][3]);
        }
    }

    float sc[16];
    #pragma unroll
    for (int s = 0; s < 16; ++s) {
        float v = tanhf(dot[s][0]) * myu[0] + tanhf(dot[s][1]) * myu[1]
                + tanhf(dot[s][2]) * myu[2] + tanhf(dot[s][3]) * myu[3];
        #pragma unroll
        for (int off = 1; off < 64; off <<= 1) v += __shfl_xor(v, off, 64);
        sc[s] = v;
    }

    float mx = sc[0];
    #pragma unroll
    for (int s = 1; s < 16; ++s) mx = fmaxf(mx, sc[s]);
    float e[16], sum = 0.f;
    #pragma unroll
    for (int s = 0; s < 16; ++s) { e[s] = expf(sc[s] - mx); sum += e[s]; }
    float inv = 1.f / sum;

    if (lane < 35) {
        float acc = 0.f;
        #pragma unroll
        for (int s = 0; s < 16; ++s) acc = fmaf(shw[s * 35 + lane], e[s] * inv, acc);
        out[(size_t)bc * 35 + lane] = elu_f(acc);
    }
}

// ---------------------------------------------------------------------------
// Fused GIN stack, split-bf16 (hi/lo). 512 threads = 8 waves.
// ---------------------------------------------------------------------------
#define APLANE (64 * 264)

__device__ __forceinline__ void gin_gemm_dev(
    const __bf16* As,
    const __bf16* __restrict__ Wg, int Kpad, int wlo, int Kout,
    const float* __restrict__ bias,
    int mode, __bf16* Ad, float* __restrict__ outg)
{
    const int lane = threadIdx.x & 63;
    const int wave = threadIdx.x >> 6;
    const int o0 = wave * 32;
    if (o0 >= ((Kout + 63) & ~63)) return;
    const int m = lane & 15, quad = lane >> 4;

    f32x4 acc[4][2];
    #pragma unroll
    for (int mi = 0; mi < 4; ++mi)
        #pragma unroll
        for (int nj = 0; nj < 2; ++nj)
            acc[mi][nj] = (f32x4){0.f, 0.f, 0.f, 0.f};

    for (int k0 = 0; k0 < Kpad; k0 += 32) {
        bf16x8 ah[4], al[4], bh[2], bl[2];
        #pragma unroll
        for (int mi = 0; mi < 4; ++mi) {
            const __bf16* ap = As + (size_t)(mi * 16 + m) * 264 + k0 + quad * 8;
            ah[mi] = *(const bf16x8*)ap;
            al[mi] = *(const bf16x8*)(ap + APLANE);
        }
        #pragma unroll
        for (int nj = 0; nj < 2; ++nj) {
            const __bf16* wp = Wg + (size_t)(o0 + nj * 16 + m) * Kpad + k0 + quad * 8;
            bh[nj] = *(const bf16x8*)wp;
            bl[nj] = *(const bf16x8*)(wp + wlo);
        }
        #pragma unroll
        for (int mi = 0; mi < 4; ++mi)
            #pragma unroll
            for (int nj = 0; nj < 2; ++nj) {
                acc[mi][nj] = __builtin_amdgcn_mfma_f32_16x16x32_bf16(
                    al[mi], bh[nj], acc[mi][nj], 0, 0, 0);
                acc[mi][nj] = __builtin_amdgcn_mfma_f32_16x16x32_bf16(
                    ah[mi], bl[nj], acc[mi][nj], 0, 0, 0);
                acc[mi][nj] = __builtin_amdgcn_mfma_f32_16x16x32_bf16(
                    ah[mi], bh[nj], acc[mi][nj], 0, 0, 0);
            }
    }

    #pragma unroll
    for (int nj = 0; nj < 2; ++nj) {
        const int o = o0 + nj * 16 + m;
        const bool ovalid = (o < Kout);
        const float bi = ovalid ? bias[o] : 0.f;
        float v[4][4];
        #pragma unroll
        for (int mi = 0; mi < 4; ++mi)
            #pragma unroll
            for (int r = 0; r < 4; ++r)
                v[mi][r] = acc[mi][nj][r] + bi;
        if (mode == 2) {
            if (ovalid) {
                #pragma unroll
                for (int mi = 0; mi < 4; ++mi)
                    #pragma unroll
                    for (int r = 0; r < 4; ++r)
                        outg[(size_t)(mi * 16 + quad * 4 + r) * Kout + o] = v[mi][r];
            }
        } else {
            float s = 0.f;
            #pragma unroll
            for (int mi = 0; mi < 4; ++mi)
                #pragma unroll
                for (int r = 0; r < 4; ++r) {
                    float rv = ovalid ? fmaxf(v[mi][r], 0.f) : 0.f;
                    v[mi][r] = rv;
                    s += rv;
                }
            if (mode == 1) {
                s += __shfl_xor(s, 16, 64);
                s += __shfl_xor(s, 32, 64);
            } else {
                s = 0.f;
            }
            #pragma unroll
            for (int mi = 0; mi < 4; ++mi)
                #pragma unroll
                for (int r = 0; r < 4; ++r) {
                    float a = v[mi][r] + s;
                    __bf16 hi = (__bf16)a;
                    size_t pos = (size_t)(mi * 16 + quad * 4 + r) * 264 + o;
                    Ad[pos] = hi;
                    Ad[APLANE + pos] = (__bf16)(a - (float)hi);
                }
        }
    }
}

__global__ __launch_bounds__(512) void gin_fused(
    const float* __restrict__ ha,
    const __bf16* __restrict__ gW0a, const __bf16* __restrict__ gW0b,
    const __bf16* __restrict__ gW1a, const __bf16* __restrict__ gW1b,
    const __bf16* __restrict__ gW2a, const __bf16* __restrict__ gW2b,
    const float* __restrict__ b0a, const float* __restrict__ b0b,
    const float* __restrict__ b1a, const float* __restrict__ b1b,
    const float* __restrict__ b2a, const float* __restrict__ b2b,
    float* __restrict__ H3)
{
    const int b = blockIdx.x, tid = threadIdx.x;
    __shared__ __align__(16) __bf16 sA[2][2 * APLANE];
    __shared__ float sS[64];
    const float* hab = ha + (size_t)b * 2240;

    if (tid < 64) {
        float s = 0.f;
        if (tid < 35)
            for (int n = 0; n < 64; ++n) s += hab[n * 35 + tid];
        sS[tid] = s;
    }
    __syncthreads();
    for (int idx = tid; idx < 64 * 64; idx += 512) {
        int n = idx >> 6, k = idx & 63;
        float a = (k < 35) ? hab[n * 35 + k] + sS[k] : 0.f;
        __bf16 hi = (__bf16)a;
        sA[0][n * 264 + k] = hi;
        sA[0][APLANE + n * 264 + k] = (__bf16)(a - (float)hi);
    }
    __syncthreads();

    gin_gemm_dev(sA[0], gW0a, 64,  16384, 256, b0a, 0, sA[1], nullptr); __syncthreads();
    gin_gemm_dev(sA[1], gW0b, 256, 65536, 256, b0b, 1, sA[0], nullptr); __syncthreads();
    gin_gemm_dev(sA[0], gW1a, 256, 65536, 256, b1a, 0, sA[1], nullptr); __syncthreads();
    gin_gemm_dev(sA[1], gW1b, 256, 65536, 256, b1b, 1, sA[0], nullptr); __syncthreads();
    gin_gemm_dev(sA[0], gW2a, 256, 16384, 35,  b2a, 0, sA[1], nullptr); __syncthreads();
    gin_gemm_dev(sA[1], gW2b, 64,  4096,  35,  b2b, 2, nullptr, H3 + (size_t)b * 2240);
}

// ---------------------------------------------------------------------------
// Classifier layer 1, fp32, K-split: grid (b=32, kc=16).
// ---------------------------------------------------------------------------
__global__ __launch_bounds__(256) void cls1_part_k(
    const float* __restrict__ H3, const float* __restrict__ w1,
    float* __restrict__ s1p)
{
    const int b  = blockIdx.x;
    const int kc = blockIdx.y;
    const int k0 = kc * 140;
    __shared__ float sH[140];
    const int tid = threadIdx.x;
    if (tid < 140) sH[tid] = H3[(size_t)b * 2240 + k0 + tid];
    __syncthreads();
    const int o = (tid >> 6) * 64 + (tid & 63);
    float a0 = 0.f, a1 = 0.f, a2 = 0.f, a3 = 0.f;
    const float* wr = w1 + (size_t)k0 * 256 + o;
    #pragma unroll
    for (int k = 0; k < 140; k += 4) {
        a0 = fmaf(sH[k],     wr[(size_t)k * 256],       a0);
        a1 = fmaf(sH[k + 1], wr[(size_t)(k + 1) * 256], a1);
        a2 = fmaf(sH[k + 2], wr[(size_t)(k + 2) * 256], a2);
        a3 = fmaf(sH[k + 3], wr[(size_t)(k + 3) * 256], a3);
    }
    s1p[((size_t)kc * 32 + b) * 256 + o] = a0 + a1 + a2 + a3;
}

// ---------------------------------------------------------------------------
// Classifier: reduce K-split partials (+bias, ELU), then layers 2-4 (fp32).
// ---------------------------------------------------------------------------
__global__ __launch_bounds__(256) void cls234_k(
    const float* __restrict__ s1p, const float* __restrict__ b1,
    const float* __restrict__ w2, const float* __restrict__ b2,
    const float* __restrict__ w3, const float* __restrict__ b3,
    const float* __restrict__ w4, const float* __restrict__ b4,
    float* __restrict__ out)
{
    const int b = blockIdx.x, tid = threadIdx.x;
    __shared__ float s1[256];
    __shared__ float part[4][64];
    __shared__ float s2[64];
    __shared__ float s3[16];
    {
        float acc = b1[tid];
        #pragma unroll
        for (int kc = 0; kc < 16; ++kc)
            acc += s1p[((size_t)kc * 32 + b) * 256 + tid];
        s1[tid] = elu_f(acc);
    }
    __syncthreads();
    {
        int kg = tid >> 6, o = tid & 63;
        float acc = 0.f;
        for (int k = kg * 64; k < kg * 64 + 64; ++k)
            acc = fmaf(s1[k], w2[k * 64 + o], acc);
        part[kg][o] = acc;
    }
    __syncthreads();
    if (tid < 64) {
        float acc = part[0][tid] + part[1][tid] + part[2][tid] + part[3][tid] + b2[tid];
        s2[tid] = elu_f(acc);
    }
    __syncthreads();
    if (tid < 16) {
        float acc = b3[tid];
        for (int k = 0; k < 64; ++k) acc = fmaf(s2[k], w3[k * 16 + tid], acc);
        s3[tid] = elu_f(acc);
    }
    __syncthreads();
    if (tid < 2) {
        float acc = b4[tid];
        for (int k = 0; k < 16; ++k) acc = fmaf(s3[k], w4[k * 2 + tid], acc);
        out[b * 2 + tid] = acc;
    }
}

// ---------------------------------------------------------------------------
extern "C" void kernel_launch(void* const* d_in, const int* in_sizes, int n_in,
                              void* d_out, int out_size, void* d_ws, size_t ws_size,
                              hipStream_t stream)
{
    const float* x     = (const float*)d_in[0];
    const float* w1    = (const float*)d_in[1];
    const float* b1    = (const float*)d_in[2];
    const float* bn1_g = (const float*)d_in[3];
    const float* bn1_b = (const float*)d_in[4];
    const float* bn1_m = (const float*)d_in[5];
    const float* bn1_v = (const float*)d_in[6];
    const float* w2    = (const float*)d_in[7];
    const float* b2    = (const float*)d_in[8];
    const float* bn2_g = (const float*)d_in[9];
    const float* bn2_b = (const float*)d_in[10];
    const float* bn2_m = (const float*)d_in[11];
    const float* bn2_v = (const float*)d_in[12];
    const float* w3    = (const float*)d_in[13];
    const float* b3    = (const float*)d_in[14];
    const float* w4    = (const float*)d_in[15];
    const float* b4    = (const float*)d_in[16];
    const float* attn_w = (const float*)d_in[17];
    const float* attn_b = (const float*)d_in[18];
    const float* attn_u = (const float*)d_in[19];
    const float* g0_w1 = (const float*)d_in[20];
    const float* g0_b1 = (const float*)d_in[21];
    const float* g0_w2 = (const float*)d_in[22];
    const float* g0_b2 = (const float*)d_in[23];
    const float* g1_w1 = (const float*)d_in[24];
    const float* g1_b1 = (const float*)d_in[25];
    const float* g1_w2 = (const float*)d_in[26];
    const float* g1_b2 = (const float*)d_in[27];
    const float* g2_w1 = (const float*)d_in[28];
    const float* g2_b1 = (const float*)d_in[29];
    const float* g2_w2 = (const float*)d_in[30];
    const float* g2_b2 = (const float*)d_in[31];
    const float* c_w1  = (const float*)d_in[32];
    const float* c_b1  = (const float*)d_in[33];
    const float* c_w2  = (const float*)d_in[34];
    const float* c_b2  = (const float*)d_in[35];
    const float* c_w3  = (const float*)d_in[36];
    const float* c_b3  = (const float*)d_in[37];
    const float* c_w4  = (const float*)d_in[38];
    const float* c_b4  = (const float*)d_in[39];
    float* out = (float*)d_out;

    char* ws = (char*)d_ws;
    __bf16* wT1  = (__bf16*)(ws + 0);
    __bf16* wT2  = (__bf16*)(ws + 163840);
    __bf16* wT3  = (__bf16*)(ws + 327680);
    __bf16* wT4  = (__bf16*)(ws + 376832);
    __bf16* h1   = (__bf16*)(ws + 425984);     // [512][192][64]
    __bf16* h4   = (__bf16*)(ws + 13008896);   // [512][35][64]
    float*  ha   = (float*)(ws + 15302656);    // [32][64][35]
    __bf16* gW0a = (__bf16*)(ws + 15589376);
    __bf16* gW0b = (__bf16*)(ws + 15654912);
    __bf16* gW1a = (__bf16*)(ws + 15917056);
    __bf16* gW1b = (__bf16*)(ws + 16179200);
    __bf16* gW2a = (__bf16*)(ws + 16441344);
    __bf16* gW2b = (__bf16*)(ws + 16506880);
    float*  H3   = (float*)(ws + 16523264);    // [32][2240]
    float*  s1p  = (float*)(ws + 16809984);    // [16][32][256]

    prep_weights<<<dim3(832), dim3(256), 0, stream>>>(w1, w2, w3, w4, wT1, wT2, wT3, wT4);
    prep_tr<<<dim3(57), dim3(256), 0, stream>>>(g0_w1, g0_w2, g1_w1, g1_w2, g2_w1, g2_w2,
                                                gW0a, gW0b, gW1a, gW1b, gW2a, gW2b);

    conv_mfma<20, 2, 1, true, 0, 1, 4, 400, 192, 2><<<dim3(512), dim3(256), 0, stream>>>(
        x, wT1, b1, bn1_g, bn1_b, bn1_m, bn1_v, h1);

    conv234_fused<<<dim3(512), dim3(128), 0, stream>>>(
        h1, wT2, b2, bn2_g, bn2_b, bn2_m, bn2_v, wT3, b3, wT4, b4, h4);

    attn_pool_k<<<dim3(512), dim3(256), 0, stream>>>(h4, attn_w, attn_b, attn_u, ha);

    gin_fused<<<dim3(32), dim3(512), 0, stream>>>(
        ha, gW0a, gW0b, gW1a, gW1b, gW2a, gW2b,
        g0_b1, g0_b2, g1_b1, g1_b2, g2_b1, g2_b2, H3);

    cls1_part_k<<<dim3(32, 16), dim3(256), 0, stream>>>(H3, c_w1, s1p);
    cls234_k<<<dim3(32), dim3(256), 0, stream>>>(s1p, c_b1, c_w2, c_b2, c_w3, c_b3,
                                                 c_w4, c_b4, out);
}